// Round 7
// baseline (664.689 us; speedup 1.0000x reference)
//
#include <hip/hip_runtime.h>
#include <math.h>

#define Tt 2048
#define Hh 16
#define Dd 128
#define ATTN 2048

typedef unsigned short u16;
typedef __attribute__((ext_vector_type(8))) short short8;
typedef __attribute__((ext_vector_type(4))) float f32x4;

__device__ __forceinline__ float bf2f(u16 h) {
    union { unsigned int u; float f; } x;
    x.u = ((unsigned int)h) << 16;
    return x.f;
}
__device__ __forceinline__ u16 f2bf(float f) {
    union { float f; unsigned int u; } x;
    x.f = f;
    unsigned int r = x.u + 0x7fffu + ((x.u >> 16) & 1u);  // RNE
    return (u16)(r >> 16);
}
// async global->LDS, 16B per lane; lptr is wave-uniform base, HW adds lane*16.
__device__ __forceinline__ void gl_lds16(const void* g, void* l) {
    __builtin_amdgcn_global_load_lds(
        (const __attribute__((address_space(1))) unsigned int*)g,
        (__attribute__((address_space(3))) unsigned int*)l, 16, 0, 0);
}

// ---- RoPE cos/sin table (reference ignores freqs_cos/sin inputs; recompute).
__global__ __launch_bounds__(256) void freq_kernel(float* __restrict__ cost,
                                                   float* __restrict__ sint) {
    int idx = blockIdx.x * 256 + threadIdx.x;   // Tt*64
    if (idx >= Tt * 64) return;
    int t = idx >> 6, i = idx & 63;
    double inv = exp(-((double)(2 * i) / 128.0) * log(10000.0));
    double ang = (double)t * inv;
    cost[idx] = (float)cos(ang);
    sint[idx] = (float)sin(ang);
}

// ---- fp32 -> bf16 bulk convert (vectorized), n4 = elems/4
__global__ __launch_bounds__(256) void cvt_kernel(const float* __restrict__ in,
                                                  u16* __restrict__ out, int n4) {
    int i = blockIdx.x * 256 + threadIdx.x;
    if (i >= n4) return;
    float4 v = *(const float4*)(in + (size_t)i * 4);
    union { ushort4 u; u16 s[4]; } pk;
    pk.s[0] = f2bf(v.x); pk.s[1] = f2bf(v.y);
    pk.s[2] = f2bf(v.z); pk.s[3] = f2bf(v.w);
    *(ushort4*)(out + (size_t)i * 4) = pk.u;
}

// ---- bf16 MFMA GEMM, 256x256 tile, BK=64, 8 waves (512 thr, 2Mx4N grid),
// counted-vmcnt deep pipeline (T3+T4), granule-XOR swizzled LDS (T2),
// setprio around MFMA clusters (T5). LDS 128 KiB dynamic (2 dbuf).
// R7 fix: FULL tile t+2 (A and B, 8 loads) staged in P4 -> every load has
// >=1.5 tiles (~2000 cyc) of flight time; entry waits vmcnt(8) so tile
// t+1's 8 loads are never drained (T4). R6 staged B(t+1) in P1/P2 with only
// ~0.7-tile lead -> entry stalls on B.
// Per K-tile t (buf d=t&1):
//   vmcnt(8); s_barrier            // tile t landed; t+1's 8 loads fly
//   P1: ds_read A mt0-3 + B (16)
//   P2: 32 MFMA (mt0-3)
//   P3: ds_read A mt4-7 (8); lgkmcnt(0)
//   s_barrier                      // all waves done reading buf d
//   P4: stage tile t+2 -> buf d (8 loads); 32 MFMA (mt4-7)
// MODE 0: fp32 (M,2048). MODE 1: bf16 (B,H,T,D). MODE 2: bf16 (B,H,D,T).
template<int MODE>
__global__ __launch_bounds__(512, 2) void gemm_mfma(const u16* __restrict__ A,
                                                    const u16* __restrict__ W,
                                                    const float* __restrict__ bias,
                                                    void* __restrict__ Cout) {
    extern __shared__ u16 lds[];   // 131072 B: [buf2][A0,A1,B0,B1][8192 u16]
    const int tid  = threadIdx.x;
    const int lane = tid & 63, w = tid >> 6;       // 8 waves
    const int l15  = lane & 15, quad = lane >> 4;
    const int wm = w >> 2, wn = w & 3;             // 2 x 4 wave grid

    const int id = blockIdx.x;                     // 256 blocks = 1/CU
    const int bx = id & 7, by = id >> 3;           // XCD id&7 owns B-panel bx
    const int m0 = by * 256, n0 = bx * 256;

    const f32x4 zero4 = {0.f, 0.f, 0.f, 0.f};
    f32x4 acc[8][4];
#pragma unroll
    for (int mt = 0; mt < 8; mt++)
#pragma unroll
        for (int nt = 0; nt < 4; nt++) acc[mt][nt] = zero4;

    // staging: thread covers row (w*16 + j*8 + lane>>3) of a 128-row half,
    // physical chunk lane&7 carries global chunk (lane&7)^(lane>>3).
    const int srow = w * 16 + (lane >> 3);
    const int gsc  = ((lane & 7) ^ (lane >> 3)) * 8;
    const u16* Ag = A + (size_t)(m0 + srow) * 2048 + gsc;
    const u16* Wg = W + (size_t)(n0 + srow) * 2048 + gsc;
    const int wB = w * 1024;                       // wave's j=0 dest (elems)

    // read-side offsets (elems): chunk = (ks*4+quad)^(row&7), row&7 == l15&7
    const int s7 = l15 & 7;
    const int cA = wm * 8192 + l15 * 64;                              // +mt*1024
    const int cB = 16384 + (wn >> 1) * 8192 + ((wn & 1) * 64 + l15) * 64;  // +nt*1024
    const int ck0 = (quad ^ s7) * 8;
    const int ck1 = ((quad ^ s7) ^ 4) * 8;

#define STAGE(tt, dd, ss) do { \
    const u16* _g = (((ss) < 2) ? Ag : Wg) + (((ss) & 1) ? (size_t)(128 * 2048) : (size_t)0) \
                    + (size_t)(tt) * 64; \
    u16* _l = lds + (dd) * 32768 + (ss) * 8192 + wB; \
    gl_lds16(_g, _l); \
    gl_lds16(_g + (size_t)8 * 2048, _l + 512); \
} while (0)

    // prologue: full tile0 -> buf0, full tile1 -> buf1  [16 loads in flight]
    STAGE(0, 0, 0); STAGE(0, 0, 1); STAGE(0, 0, 2); STAGE(0, 0, 3);
    STAGE(1, 1, 0); STAGE(1, 1, 1); STAGE(1, 1, 2); STAGE(1, 1, 3);

    short8 af[4][2], bf[4][2];
    for (int t = 0; t < 32; t++) {
        const int d = t & 1;
        const u16* bufd = lds + d * 32768;

        // entry: wait this tile's 8 loads; t+1's 8 stay in flight (T4)
        if (t < 31) { asm volatile("s_waitcnt vmcnt(8)" ::: "memory"); }
        else        { asm volatile("s_waitcnt vmcnt(0)" ::: "memory"); }
        __builtin_amdgcn_sched_barrier(0);
        __builtin_amdgcn_s_barrier();
        __builtin_amdgcn_sched_barrier(0);

        // P1: read A mt0-3 (8) + B all (8)
#pragma unroll
        for (int mt = 0; mt < 4; mt++) {
            af[mt][0] = *(const short8*)(bufd + cA + mt * 1024 + ck0);
            af[mt][1] = *(const short8*)(bufd + cA + mt * 1024 + ck1);
        }
#pragma unroll
        for (int nt = 0; nt < 4; nt++) {
            bf[nt][0] = *(const short8*)(bufd + cB + nt * 1024 + ck0);
            bf[nt][1] = *(const short8*)(bufd + cB + nt * 1024 + ck1);
        }
        // P2: MFMA mt0-3
        __builtin_amdgcn_s_setprio(1);
#pragma unroll
        for (int mt = 0; mt < 4; mt++)
#pragma unroll
            for (int nt = 0; nt < 4; nt++) {
                acc[mt][nt] = __builtin_amdgcn_mfma_f32_16x16x32_bf16(
                    af[mt][0], bf[nt][0], acc[mt][nt], 0, 0, 0);
                acc[mt][nt] = __builtin_amdgcn_mfma_f32_16x16x32_bf16(
                    af[mt][1], bf[nt][1], acc[mt][nt], 0, 0, 0);
            }
        __builtin_amdgcn_s_setprio(0);
        // P3: read A mt4-7 (8); all LDS reads of buf d must complete
#pragma unroll
        for (int mt = 0; mt < 4; mt++) {
            af[mt][0] = *(const short8*)(bufd + cA + (mt + 4) * 1024 + ck0);
            af[mt][1] = *(const short8*)(bufd + cA + (mt + 4) * 1024 + ck1);
        }
        asm volatile("s_waitcnt lgkmcnt(0)" ::: "memory");
        __builtin_amdgcn_sched_barrier(0);
        __builtin_amdgcn_s_barrier();
        __builtin_amdgcn_sched_barrier(0);
        // P4: stage FULL tile t+2 -> buf d (dead after mid-barrier); MFMA mt4-7
        if (t + 2 < 32) {
            STAGE(t + 2, d, 0); STAGE(t + 2, d, 1);
            STAGE(t + 2, d, 2); STAGE(t + 2, d, 3);
        }
        __builtin_amdgcn_s_setprio(1);
#pragma unroll
        for (int mt = 0; mt < 4; mt++)
#pragma unroll
            for (int nt = 0; nt < 4; nt++) {
                acc[mt + 4][nt] = __builtin_amdgcn_mfma_f32_16x16x32_bf16(
                    af[mt][0], bf[nt][0], acc[mt + 4][nt], 0, 0, 0);
                acc[mt + 4][nt] = __builtin_amdgcn_mfma_f32_16x16x32_bf16(
                    af[mt][1], bf[nt][1], acc[mt + 4][nt], 0, 0, 0);
            }
        __builtin_amdgcn_s_setprio(0);
    }
#undef STAGE

    float bn[4];
#pragma unroll
    for (int nt = 0; nt < 4; nt++) bn[nt] = bias[n0 + wn * 64 + nt * 16 + l15];

    if (MODE == 0) {
        float* C = (float*)Cout;
#pragma unroll
        for (int mt = 0; mt < 8; mt++) {
            int m = m0 + wm * 128 + mt * 16 + quad * 4;
#pragma unroll
            for (int nt = 0; nt < 4; nt++) {
                int n = n0 + wn * 64 + nt * 16 + l15;
#pragma unroll
                for (int r = 0; r < 4; r++)
                    C[(size_t)(m + r) * 2048 + n] = acc[mt][nt][r] + bn[nt];
            }
        }
    } else if (MODE == 1) {
        u16* C = (u16*)Cout;
#pragma unroll
        for (int mt = 0; mt < 8; mt++) {
            int m = m0 + wm * 128 + mt * 16 + quad * 4;
            int b = m >> 11, tr = m & 2047;
#pragma unroll
            for (int nt = 0; nt < 4; nt++) {
                int n = n0 + wn * 64 + nt * 16 + l15;
                int h = n >> 7, dd = n & 127;
                size_t base = ((size_t)(b * Hh + h) * Tt + tr) * Dd + dd;
#pragma unroll
                for (int r = 0; r < 4; r++)
                    C[base + (size_t)r * Dd] = f2bf(acc[mt][nt][r] + bn[nt]);
            }
        }
    } else {  // MODE 2: V transposed (B,H,D,T), pack 4 consecutive t per lane
        u16* C = (u16*)Cout;
        const int b = m0 >> 11;
#pragma unroll
        for (int mt = 0; mt < 8; mt++) {
            int tloc = (m0 & 2047) + wm * 128 + mt * 16 + quad * 4;
#pragma unroll
            for (int nt = 0; nt < 4; nt++) {
                int n = n0 + wn * 64 + nt * 16 + l15;
                int h = n >> 7, dd = n & 127;
                union { ushort4 u; u16 s[4]; } pk;
#pragma unroll
                for (int r = 0; r < 4; r++) pk.s[r] = f2bf(acc[mt][nt][r] + bn[nt]);
                *(ushort4*)&C[((size_t)(b * Hh + h) * Dd + dd) * Tt + tloc] = pk.u;
            }
        }
    }
}

// ---- RoPE in-place on q,k bf16 (B,H,T,D), vectorized: 4 pairs (16B) per lane.
// Q additionally pre-scaled by 1/sqrt(D) * log2(e): flash softmax runs in the
// exp2 domain with no per-element scale mul (rotation is linear -> legal fold).
#define QSCALE 0.12751743f
__global__ __launch_bounds__(256) void rope_kernel(u16* __restrict__ q,
                                                   u16* __restrict__ k,
                                                   const float* __restrict__ cost,
                                                   const float* __restrict__ sint) {
    int p = blockIdx.x * 256 + threadIdx.x;    // B*H*T*16 groups of 4 pairs
    int g4 = (p & 15) * 4;                     // first pair index within row
    int t  = (p >> 4) & 2047;
    float4 c4 = *(const float4*)(cost + t * 64 + g4);
    float4 s4 = *(const float4*)(sint + t * 64 + g4);
    float cc[4] = {c4.x, c4.y, c4.z, c4.w};
    float ss[4] = {s4.x, s4.y, s4.z, s4.w};
    size_t off = (size_t)p * 8;                // 8 u16 = 4 pairs
    short8 qv = *(short8*)(q + off);
    short8 kv = *(short8*)(k + off);
    short8 qo, ko;
#pragma unroll
    for (int j = 0; j < 4; j++) {
        float q0 = bf2f((u16)qv[2 * j]), q1 = bf2f((u16)qv[2 * j + 1]);
        qo[2 * j]     = (short)f2bf((q0 * cc[j] - q1 * ss[j]) * QSCALE);
        qo[2 * j + 1] = (short)f2bf((q0 * ss[j] + q1 * cc[j]) * QSCALE);
        float k0 = bf2f((u16)kv[2 * j]), k1 = bf2f((u16)kv[2 * j + 1]);
        ko[2 * j]     = (short)f2bf(k0 * cc[j] - k1 * ss[j]);
        ko[2 * j + 1] = (short)f2bf(k0 * ss[j] + k1 * cc[j]);
    }
    *(short8*)(q + off) = qo;
    *(short8*)(k + off) = ko;
}

// ---- MFMA flash attention (causal), R5 structure (measured 211us): R0
// double-barrier staging + head-affine XCD remap + T5 setprio + tree
// reductions + defer-max. UNCHANGED this round.
__global__ __launch_bounds__(256) void flash_mfma(const u16* __restrict__ Q,
                                                  const u16* __restrict__ K,
                                                  const u16* __restrict__ Vt,
                                                  u16* __restrict__ O) {
    __shared__ u16 Ks[64 * 128];      // [kp][d], granule-XOR-swizzled by kp&15
    __shared__ u16 Vs[128 * 64];      // [d][kp], granule-XOR-swizzled by d&7
    __shared__ u16 Ps[4][32 * 72];    // per-wave P [q][kp], stride 72
    __shared__ float als[4][32];
    __shared__ float lls[4][32];
    const int tid  = threadIdx.x;
    const int lane = tid & 63, w = tid >> 6;
    const int l15  = lane & 15, quad = lane >> 4;

    // head-affine XCD remap: XCD x (= id&7) handles heads 8x..8x+7
    const int id  = blockIdx.x;                // 512 blocks
    const int bh  = (id & 7) * 8 + ((id >> 3) & 7);
    const int bxp = id >> 6;                   // 0..7 pairing slot

    // staging pointers (wave w owns chunks 4w..4w+3 of each buffer); bh-only
    const u16* Kg[4]; const u16* Vg[4];
    u16* KsD[4]; u16* VsD[4];
#pragma unroll
    for (int cc = 0; cc < 4; cc++) {
        int kp = w * 16 + cc * 4 + quad;
        int gs = l15 ^ (cc * 4 + quad);
        Kg[cc]  = K + ((size_t)bh * Tt + kp) * Dd + gs * 8;
        KsD[cc] = Ks + (w * 4 + cc) * 512;
        int d  = w * 32 + cc * 8 + (lane >> 3);
        int gv = (lane & 7) ^ (lane >> 3);
        Vg[cc]  = Vt + ((size_t)bh * Dd + d) * Tt + gv * 8;
        VsD[cc] = Vs + (w * 4 + cc) * 512;
    }

    const f32x4 zero4 = {0.f, 0.f, 0.f, 0.f};

    for (int ph = 0; ph < 2; ph++) {
        const int qt = ph ? bxp : 15 - bxp;
        const int q0 = qt * 128;

        // Q fragments (B-operand of S^T): q=nt*16+l15, d=ks*32+quad*8
        short8 qf[2][4];
        const u16* Qb = Q + ((size_t)bh * Tt + q0 + w * 32 + l15) * Dd + quad * 8;
#pragma unroll
        for (int nt = 0; nt < 2; nt++)
#pragma unroll
            for (int ks = 0; ks < 4; ks++)
                qf[nt][ks] = *(const short8*)(Qb + nt * 16 * Dd + ks * 32);

        f32x4 Oa[2][8];
#pragma unroll
        for (int mo = 0; mo < 2; mo++)
#pragma unroll
            for (int nt2 = 0; nt2 < 8; nt2++) Oa[mo][nt2] = zero4;
        float mrow[2] = {-INFINITY, -INFINITY};
        float lrow[2] = {0.f, 0.f};

        const int nkt = 2 * qt + 2;
        for (int kt = 0; kt < nkt; kt++) {
            __syncthreads();
#pragma unroll
            for (int cc = 0; cc < 4; cc++) gl_lds16(Kg[cc] + (size_t)kt * 64 * Dd, KsD[cc]);
#pragma unroll
            for (int cc = 0; cc < 4; cc++) gl_lds16(Vg[cc] + kt * 64, VsD[cc]);
            __syncthreads();

            // wave-level skip: tile fully masked for this wave's 32 q-rows
            if (kt * 64 > q0 + w * 32 + 31) continue;  // barriers already done

            // S^T = K * Q^T : rows kp = mt*16+quad*4+r, cols q = nt*16+l15
            f32x4 sc[4][2];
#pragma unroll
            for (int mt = 0; mt < 4; mt++) { sc[mt][0] = zero4; sc[mt][1] = zero4; }
            __builtin_amdgcn_s_setprio(1);
#pragma unroll
            for (int ks = 0; ks < 4; ks++) {
                short8 kf[4];
#pragma unroll
                for (int mt = 0; mt < 4; mt++)
                    kf[mt] = *(const short8*)(Ks + (mt * 16 + l15) * 128 +
                                              (((ks * 4 + quad) ^ l15) * 8));
#pragma unroll
                for (int mt = 0; mt < 4; mt++) {
                    sc[mt][0] = __builtin_amdgcn_mfma_f32_16x16x32_bf16(kf[mt], qf[0][ks], sc[mt][0], 0, 0, 0);
                    sc[mt][1] = __builtin_amdgcn_mfma_f32_16x16x32_bf16(kf[mt], qf[1][ks], sc[mt][1], 0, 0, 0);
                }
            }
            __builtin_amdgcn_s_setprio(0);

            const bool diag = (kt * 64 + 63 > q0 + w * 32);
            // online softmax in exp2 domain (scale*log2e pre-folded into Q)
#pragma unroll
            for (int nt = 0; nt < 2; nt++) {
                const int q_g = q0 + w * 32 + nt * 16 + l15;
                float sv[16];
#pragma unroll
                for (int mt = 0; mt < 4; mt++)
#pragma unroll
                    for (int r = 0; r < 4; r++)
                        sv[mt * 4 + r] = sc[mt][nt][r];
                if (diag) {
#pragma unroll
                    for (int mt = 0; mt < 4; mt++)
#pragma unroll
                        for (int r = 0; r < 4; r++) {
                            int kp_g = kt * 64 + mt * 16 + quad * 4 + r;
                            if (kp_g > q_g) sv[mt * 4 + r] = -INFINITY;
                        }
                }
                // tree max (depth 4)
                float m8[8], m4[4];
#pragma unroll
                for (int e = 0; e < 8; e++) m8[e] = fmaxf(sv[e], sv[e + 8]);
#pragma unroll
                for (int e = 0; e < 4; e++) m4[e] = fmaxf(m8[e], m8[e + 4]);
                float mx = fmaxf(fmaxf(m4[0], m4[1]), fmaxf(m4[2], m4[3]));
                mx = fmaxf(mx, __shfl_xor(mx, 16, 64));
                mx = fmaxf(mx, __shfl_xor(mx, 32, 64));
                float mnew = fmaxf(mrow[nt], mx);
                // defer-max (T13): keep old running max when growth <= 8
                mnew = (mnew - mrow[nt] <= 8.f) ? mrow[nt] : mnew;
                float alpha = exp2f(mrow[nt] - mnew);
                float pv[16];
#pragma unroll
                for (int e = 0; e < 16; e++) pv[e] = exp2f(sv[e] - mnew);
                // tree sum (depth 4)
                float s8[8], s4[4];
#pragma unroll
                for (int e = 0; e < 8; e++) s8[e] = pv[e] + pv[e + 8];
#pragma unroll
                for (int e = 0; e < 4; e++) s4[e] = s8[e] + s8[e + 4];
                float rs = (s4[0] + s4[1]) + (s4[2] + s4[3]);
                rs += __shfl_xor(rs, 16, 64);
                rs += __shfl_xor(rs, 32, 64);
                lrow[nt] = lrow[nt] * alpha + rs;
                mrow[nt] = mnew;
                if (quad == 0) als[w][nt * 16 + l15] = alpha;
#pragma unroll
                for (int mt = 0; mt < 4; mt++) {
                    union { ushort4 u; u16 s[4]; } pk;
#pragma unroll
                    for (int r = 0; r < 4; r++) pk.s[r] = f2bf(pv[mt * 4 + r]);
                    *(ushort4*)&Ps[w][(nt * 16 + l15) * 72 + mt * 16 + quad * 4] = pk.u;
                }
            }

            // rescale O by alpha; wave-uniform skip when all alphas == 1
            float ao[2][4];
            bool need = false;
#pragma unroll
            for (int mo = 0; mo < 2; mo++)
#pragma unroll
                for (int r = 0; r < 4; r++) {
                    ao[mo][r] = als[w][mo * 16 + quad * 4 + r];
                    need |= (ao[mo][r] != 1.f);
                }
            if (__any(need)) {
#pragma unroll
                for (int mo = 0; mo < 2; mo++)
#pragma unroll
                    for (int nt2 = 0; nt2 < 8; nt2++)
#pragma unroll
                        for (int r = 0; r < 4; r++) Oa[mo][nt2][r] *= ao[mo][r];
            }

            // O += P * V
            __builtin_amdgcn_s_setprio(1);
#pragma unroll
            for (int ks2 = 0; ks2 < 2; ks2++) {
                short8 pf[2];
#pragma unroll
                for (int mo = 0; mo < 2; mo++)
                    pf[mo] = *(const short8*)&Ps[w][(mo * 16 + l15) * 72 + ks2 * 32 + quad * 8];
#pragma unroll
                for (int nt2 = 0; nt2 < 8; nt2++) {
                    short8 vf = *(const short8*)(Vs + (nt2 * 16 + l15) * 64 +
                                                 (((ks2 * 4 + quad) ^ (l15 & 7)) * 8));
                    Oa[0][nt2] = __builtin_amdgcn_mfma_f32_16x16x32_bf16(pf[0], vf, Oa[0][nt2], 0, 0, 0);
                    Oa[1][nt2] = __builtin_amdgcn_mfma_f32_16x16x32_bf16(pf[1], vf, Oa[1][nt2], 0, 0, 0);
                }
            }
            __builtin_amdgcn_s_setprio(0);
        }

        // epilogue: normalize by l, store bf16 (B,T,ATTN)
        if (quad == 0) { lls[w][l15] = lrow[0]; lls[w][16 + l15] = lrow[1]; }
        float li[2][4];
#pragma unroll
        for (int mo = 0; mo < 2; mo++)
#pragma unroll
            for (int r = 0; r < 4; r++) li[mo][r] = 1.f / lls[w][mo * 16 + quad * 4 + r];
        const int b = bh >> 4, h = bh & 15;
#pragma unroll
        for (int mo = 0; mo < 2; mo++)
#pragma unroll
            for (int r = 0; r < 4; r++) {
                size_t ro = ((size_t)b * Tt + q0 + w * 32 + mo * 16 + quad * 4 + r) * ATTN
                            + h * Dd;
#pragma unroll
                for (int nt2 = 0; nt2 < 8; nt2++)
                    O[ro + nt2 * 16 + l15] = f2bf(Oa[mo][nt2][r] * li[mo][r]);
            }
    }
}

extern "C" void kernel_launch(void* const* d_in, const int* in_sizes, int n_in,
                              void* d_out, int out_size, void* d_ws, size_t ws_size,
                              hipStream_t stream) {
    const float* x    = (const float*)d_in[0];
    const float* wq_w = (const float*)d_in[3];
    const float* wq_b = (const float*)d_in[4];
    const float* wk_w = (const float*)d_in[5];
    const float* wk_b = (const float*)d_in[6];
    const float* wv_w = (const float*)d_in[7];
    const float* wv_b = (const float*)d_in[8];
    const float* wo_w = (const float*)d_in[9];
    const float* wo_b = (const float*)d_in[10];

    char* ws = (char*)d_ws;
    u16*   qb  = (u16*)(ws);                    // 32 MiB bf16 (B,H,T,D)
    u16*   kb  = (u16*)(ws + 33554432);         // 32 MiB bf16 (B,H,T,D)
    u16*   vtb = (u16*)(ws + 67108864);         // 32 MiB bf16 (B,H,D,T)
    u16*   xb  = (u16*)(ws + 100663296);        // 32 MiB bf16 x (8192x2048)
    u16*   obb = xb;                            // flash out aliases xb (x dead)
    u16*   wqb = (u16*)(ws + 134217728);        // 8 MiB each
    u16*   wkb = (u16*)(ws + 142606336);
    u16*   wvb = (u16*)(ws + 150994944);
    u16*   wob = (u16*)(ws + 159383552);
    float* ct  = (float*)(ws + 167772160);      // 512 KiB
    float* st  = (float*)(ws + 168296448);      // 512 KiB

    freq_kernel<<<512, 256, 0, stream>>>(ct, st);
    cvt_kernel<<<16384, 256, 0, stream>>>(x, xb, 4194304);
    cvt_kernel<<<4096, 256, 0, stream>>>(wq_w, wqb, 1048576);
    cvt_kernel<<<4096, 256, 0, stream>>>(wk_w, wkb, 1048576);
    cvt_kernel<<<4096, 256, 0, stream>>>(wv_w, wvb, 1048576);
    cvt_kernel<<<4096, 256, 0, stream>>>(wo_w, wob, 1048576);

    gemm_mfma<1><<<256, 512, 131072, stream>>>(xb, wqb, wq_b, qb);
    gemm_mfma<1><<<256, 512, 131072, stream>>>(xb, wkb, wk_b, kb);
    gemm_mfma<2><<<256, 512, 131072, stream>>>(xb, wvb, wv_b, vtb);
    rope_kernel<<<8192, 256, 0, stream>>>(qb, kb, ct, st);
    flash_mfma<<<512, 256, 0, stream>>>(qb, kb, vtb, obb);
    gemm_mfma<0><<<256, 512, 131072, stream>>>(obb, wob, wo_b, (float*)d_out);
}

// Round 8
// 657.976 us; speedup vs baseline: 1.0102x; 1.0102x over previous
//
#include <hip/hip_runtime.h>
#include <math.h>

#define Tt 2048
#define Hh 16
#define Dd 128
#define ATTN 2048

typedef unsigned short u16;
typedef __attribute__((ext_vector_type(8))) short short8;
typedef __attribute__((ext_vector_type(4))) float f32x4;

__device__ __forceinline__ float bf2f(u16 h) {
    union { unsigned int u; float f; } x;
    x.u = ((unsigned int)h) << 16;
    return x.f;
}
__device__ __forceinline__ u16 f2bf(float f) {
    union { float f; unsigned int u; } x;
    x.f = f;
    unsigned int r = x.u + 0x7fffu + ((x.u >> 16) & 1u);  // RNE
    return (u16)(r >> 16);
}
// async global->LDS, 16B per lane; lptr is wave-uniform base, HW adds lane*16.
__device__ __forceinline__ void gl_lds16(const void* g, void* l) {
    __builtin_amdgcn_global_load_lds(
        (const __attribute__((address_space(1))) unsigned int*)g,
        (__attribute__((address_space(3))) unsigned int*)l, 16, 0, 0);
}

// ---- RoPE cos/sin table (reference ignores freqs_cos/sin inputs; recompute).
__global__ __launch_bounds__(256) void freq_kernel(float* __restrict__ cost,
                                                   float* __restrict__ sint) {
    int idx = blockIdx.x * 256 + threadIdx.x;   // Tt*64
    if (idx >= Tt * 64) return;
    int t = idx >> 6, i = idx & 63;
    double inv = exp(-((double)(2 * i) / 128.0) * log(10000.0));
    double ang = (double)t * inv;
    cost[idx] = (float)cos(ang);
    sint[idx] = (float)sin(ang);
}

// ---- fp32 -> bf16 bulk convert (vectorized), n4 = elems/4
__global__ __launch_bounds__(256) void cvt_kernel(const float* __restrict__ in,
                                                  u16* __restrict__ out, int n4) {
    int i = blockIdx.x * 256 + threadIdx.x;
    if (i >= n4) return;
    float4 v = *(const float4*)(in + (size_t)i * 4);
    union { ushort4 u; u16 s[4]; } pk;
    pk.s[0] = f2bf(v.x); pk.s[1] = f2bf(v.y);
    pk.s[2] = f2bf(v.z); pk.s[3] = f2bf(v.w);
    *(ushort4*)(out + (size_t)i * 4) = pk.u;
}

// ---- bf16 MFMA GEMM, 256x256 tile, BK=64, 8 waves (512 thr, 2Mx4N grid).
// R8: FINE-PHASE schedule (m201 port): 4 phases per K-tile, 16 MFMA each,
// per-phase {ds_read quarter || stage} -> barrier -> lgkm(0) -> setprio ->
// MFMA -> barrier. Mechanism (m196/m233): with 2 waves/SIMD the two waves
// occupy DIFFERENT sub-phases (one reading LDS, one in MFMA) -> LDS and
// matrix pipes overlap toward max() instead of sum(); T5 arbitration pays.
// Staging: tile t+1 -> buf e, issued across phases 1-3 (buf e drained at end
// of tile t-1; entry barrier orders all waves' drains before any write).
// Entry vmcnt(0): tile t's loads had a full tile (~3000 cyc) to land.
// MODE 0: fp32 (M,2048). MODE 1: bf16 (B,H,T,D). MODE 2: bf16 (B,H,D,T).
template<int MODE>
__global__ __launch_bounds__(512, 2) void gemm_mfma(const u16* __restrict__ A,
                                                    const u16* __restrict__ W,
                                                    const float* __restrict__ bias,
                                                    void* __restrict__ Cout) {
    extern __shared__ u16 lds[];   // 131072 B: [buf2][A0,A1,B0,B1][8192 u16]
    const int tid  = threadIdx.x;
    const int lane = tid & 63, w = tid >> 6;       // 8 waves
    const int l15  = lane & 15, quad = lane >> 4;
    const int wm = w >> 2, wn = w & 3;             // 2 x 4 wave grid

    const int id = blockIdx.x;                     // 256 blocks = 1/CU
    const int bx = id & 7, by = id >> 3;           // XCD id&7 owns B-panel bx
    const int m0 = by * 256, n0 = bx * 256;

    const f32x4 zero4 = {0.f, 0.f, 0.f, 0.f};
    f32x4 acc[8][4];
#pragma unroll
    for (int mt = 0; mt < 8; mt++)
#pragma unroll
        for (int nt = 0; nt < 4; nt++) acc[mt][nt] = zero4;

    // staging: thread covers row (w*16 + j*8 + lane>>3) of a 128-row half,
    // physical chunk lane&7 carries global chunk (lane&7)^(lane>>3).
    const int srow = w * 16 + (lane >> 3);
    const int gsc  = ((lane & 7) ^ (lane >> 3)) * 8;
    const u16* Ag = A + (size_t)(m0 + srow) * 2048 + gsc;
    const u16* Wg = W + (size_t)(n0 + srow) * 2048 + gsc;
    const int wB = w * 1024;                       // wave's j=0 dest (elems)

    // read-side offsets (elems): chunk = (ks*4+quad)^(row&7), row&7 == l15&7
    const int s7 = l15 & 7;
    const int cA = wm * 8192 + l15 * 64;                              // +mt*1024
    const int cB = 16384 + (wn >> 1) * 8192 + ((wn & 1) * 64 + l15) * 64;  // +nt*1024
    const int ck0 = (quad ^ s7) * 8;
    const int ck1 = ((quad ^ s7) ^ 4) * 8;

#define STAGE(tt, dd, ss) do { \
    const u16* _g = (((ss) < 2) ? Ag : Wg) + (((ss) & 1) ? (size_t)(128 * 2048) : (size_t)0) \
                    + (size_t)(tt) * 64; \
    u16* _l = lds + (dd) * 32768 + (ss) * 8192 + wB; \
    gl_lds16(_g, _l); \
    gl_lds16(_g + (size_t)8 * 2048, _l + 512); \
} while (0)

    // prologue: full tile0 -> buf0 (8 loads in flight)
    STAGE(0, 0, 0); STAGE(0, 0, 1); STAGE(0, 0, 2); STAGE(0, 0, 3);

    short8 afQ[4], bfr[4][2];
    for (int t = 0; t < 32; t++) {
        const int d = t & 1, e = d ^ 1;
        const u16* bufd = lds + d * 32768;
        const bool pf = (t + 1 < 32);

        // entry: tile t's 8 loads landed (issued one full tile ago)
        asm volatile("s_waitcnt vmcnt(0)" ::: "memory");
        __builtin_amdgcn_sched_barrier(0);
        __builtin_amdgcn_s_barrier();
        __builtin_amdgcn_sched_barrier(0);

        // ---- phase 1: read Q1 (af mt0-3 kx0, bf kx0); stage A(t+1)->buf e
#pragma unroll
        for (int i = 0; i < 4; i++)
            afQ[i] = *(const short8*)(bufd + cA + i * 1024 + ck0);
#pragma unroll
        for (int i = 0; i < 4; i++)
            bfr[i][0] = *(const short8*)(bufd + cB + i * 1024 + ck0);
        if (pf) { STAGE(t + 1, e, 0); STAGE(t + 1, e, 1); }
        __builtin_amdgcn_sched_barrier(0);
        __builtin_amdgcn_s_barrier();
        asm volatile("s_waitcnt lgkmcnt(0)" ::: "memory");
        __builtin_amdgcn_sched_barrier(0);
        __builtin_amdgcn_s_setprio(1);
#pragma unroll
        for (int i = 0; i < 4; i++)
#pragma unroll
            for (int j = 0; j < 4; j++)
                acc[i][j] = __builtin_amdgcn_mfma_f32_16x16x32_bf16(
                    afQ[i], bfr[j][0], acc[i][j], 0, 0, 0);
        __builtin_amdgcn_s_setprio(0);
        __builtin_amdgcn_sched_barrier(0);
        __builtin_amdgcn_s_barrier();
        __builtin_amdgcn_sched_barrier(0);

        // ---- phase 2: read af mt4-7 kx0; stage B-h0(t+1)
#pragma unroll
        for (int i = 0; i < 4; i++)
            afQ[i] = *(const short8*)(bufd + cA + (i + 4) * 1024 + ck0);
        if (pf) STAGE(t + 1, e, 2);
        __builtin_amdgcn_sched_barrier(0);
        __builtin_amdgcn_s_barrier();
        asm volatile("s_waitcnt lgkmcnt(0)" ::: "memory");
        __builtin_amdgcn_sched_barrier(0);
        __builtin_amdgcn_s_setprio(1);
#pragma unroll
        for (int i = 0; i < 4; i++)
#pragma unroll
            for (int j = 0; j < 4; j++)
                acc[i + 4][j] = __builtin_amdgcn_mfma_f32_16x16x32_bf16(
                    afQ[i], bfr[j][0], acc[i + 4][j], 0, 0, 0);
        __builtin_amdgcn_s_setprio(0);
        __builtin_amdgcn_sched_barrier(0);
        __builtin_amdgcn_s_barrier();
        __builtin_amdgcn_sched_barrier(0);

        // ---- phase 3: read Q3 (af mt0-3 kx1, bf kx1); stage B-h1(t+1)
#pragma unroll
        for (int i = 0; i < 4; i++)
            afQ[i] = *(const short8*)(bufd + cA + i * 1024 + ck1);
#pragma unroll
        for (int i = 0; i < 4; i++)
            bfr[i][1] = *(const short8*)(bufd + cB + i * 1024 + ck1);
        if (pf) STAGE(t + 1, e, 3);
        __builtin_amdgcn_sched_barrier(0);
        __builtin_amdgcn_s_barrier();
        asm volatile("s_waitcnt lgkmcnt(0)" ::: "memory");
        __builtin_amdgcn_sched_barrier(0);
        __builtin_amdgcn_s_setprio(1);
#pragma unroll
        for (int i = 0; i < 4; i++)
#pragma unroll
            for (int j = 0; j < 4; j++)
                acc[i][j] = __builtin_amdgcn_mfma_f32_16x16x32_bf16(
                    afQ[i], bfr[j][1], acc[i][j], 0, 0, 0);
        __builtin_amdgcn_s_setprio(0);
        __builtin_amdgcn_sched_barrier(0);
        __builtin_amdgcn_s_barrier();
        __builtin_amdgcn_sched_barrier(0);

        // ---- phase 4: read af mt4-7 kx1
#pragma unroll
        for (int i = 0; i < 4; i++)
            afQ[i] = *(const short8*)(bufd + cA + (i + 4) * 1024 + ck1);
        __builtin_amdgcn_sched_barrier(0);
        __builtin_amdgcn_s_barrier();
        asm volatile("s_waitcnt lgkmcnt(0)" ::: "memory");
        __builtin_amdgcn_sched_barrier(0);
        __builtin_amdgcn_s_setprio(1);
#pragma unroll
        for (int i = 0; i < 4; i++)
#pragma unroll
            for (int j = 0; j < 4; j++)
                acc[i + 4][j] = __builtin_amdgcn_mfma_f32_16x16x32_bf16(
                    afQ[i], bfr[j][1], acc[i + 4][j], 0, 0, 0);
        __builtin_amdgcn_s_setprio(0);
        __builtin_amdgcn_sched_barrier(0);
        __builtin_amdgcn_s_barrier();
        __builtin_amdgcn_sched_barrier(0);
    }
#undef STAGE

    float bn[4];
#pragma unroll
    for (int nt = 0; nt < 4; nt++) bn[nt] = bias[n0 + wn * 64 + nt * 16 + l15];

    if (MODE == 0) {
        float* C = (float*)Cout;
#pragma unroll
        for (int mt = 0; mt < 8; mt++) {
            int m = m0 + wm * 128 + mt * 16 + quad * 4;
#pragma unroll
            for (int nt = 0; nt < 4; nt++) {
                int n = n0 + wn * 64 + nt * 16 + l15;
#pragma unroll
                for (int r = 0; r < 4; r++)
                    C[(size_t)(m + r) * 2048 + n] = acc[mt][nt][r] + bn[nt];
            }
        }
    } else if (MODE == 1) {
        u16* C = (u16*)Cout;
#pragma unroll
        for (int mt = 0; mt < 8; mt++) {
            int m = m0 + wm * 128 + mt * 16 + quad * 4;
            int b = m >> 11, tr = m & 2047;
#pragma unroll
            for (int nt = 0; nt < 4; nt++) {
                int n = n0 + wn * 64 + nt * 16 + l15;
                int h = n >> 7, dd = n & 127;
                size_t base = ((size_t)(b * Hh + h) * Tt + tr) * Dd + dd;
#pragma unroll
                for (int r = 0; r < 4; r++)
                    C[base + (size_t)r * Dd] = f2bf(acc[mt][nt][r] + bn[nt]);
            }
        }
    } else {  // MODE 2: V transposed (B,H,D,T), pack 4 consecutive t per lane
        u16* C = (u16*)Cout;
        const int b = m0 >> 11;
#pragma unroll
        for (int mt = 0; mt < 8; mt++) {
            int tloc = (m0 & 2047) + wm * 128 + mt * 16 + quad * 4;
#pragma unroll
            for (int nt = 0; nt < 4; nt++) {
                int n = n0 + wn * 64 + nt * 16 + l15;
                int h = n >> 7, dd = n & 127;
                union { ushort4 u; u16 s[4]; } pk;
#pragma unroll
                for (int r = 0; r < 4; r++) pk.s[r] = f2bf(acc[mt][nt][r] + bn[nt]);
                *(ushort4*)&C[((size_t)(b * Hh + h) * Dd + dd) * Tt + tloc] = pk.u;
            }
        }
    }
}

// ---- RoPE in-place on q,k bf16 (B,H,T,D), vectorized: 4 pairs (16B) per lane.
// Q additionally pre-scaled by 1/sqrt(D) * log2(e): flash softmax runs in the
// exp2 domain with no per-element scale mul (rotation is linear -> legal fold).
#define QSCALE 0.12751743f
__global__ __launch_bounds__(256) void rope_kernel(u16* __restrict__ q,
                                                   u16* __restrict__ k,
                                                   const float* __restrict__ cost,
                                                   const float* __restrict__ sint) {
    int p = blockIdx.x * 256 + threadIdx.x;    // B*H*T*16 groups of 4 pairs
    int g4 = (p & 15) * 4;                     // first pair index within row
    int t  = (p >> 4) & 2047;
    float4 c4 = *(const float4*)(cost + t * 64 + g4);
    float4 s4 = *(const float4*)(sint + t * 64 + g4);
    float cc[4] = {c4.x, c4.y, c4.z, c4.w};
    float ss[4] = {s4.x, s4.y, s4.z, s4.w};
    size_t off = (size_t)p * 8;                // 8 u16 = 4 pairs
    short8 qv = *(short8*)(q + off);
    short8 kv = *(short8*)(k + off);
    short8 qo, ko;
#pragma unroll
    for (int j = 0; j < 4; j++) {
        float q0 = bf2f((u16)qv[2 * j]), q1 = bf2f((u16)qv[2 * j + 1]);
        qo[2 * j]     = (short)f2bf((q0 * cc[j] - q1 * ss[j]) * QSCALE);
        qo[2 * j + 1] = (short)f2bf((q0 * ss[j] + q1 * cc[j]) * QSCALE);
        float k0 = bf2f((u16)kv[2 * j]), k1 = bf2f((u16)kv[2 * j + 1]);
        ko[2 * j]     = (short)f2bf(k0 * cc[j] - k1 * ss[j]);
        ko[2 * j + 1] = (short)f2bf(k0 * ss[j] + k1 * cc[j]);
    }
    *(short8*)(q + off) = qo;
    *(short8*)(k + off) = ko;
}

// ---- MFMA flash attention (causal), R5 structure (measured 211us): R0
// double-barrier staging + head-affine XCD remap + T5 setprio + tree
// reductions + defer-max. UNCHANGED this round.
__global__ __launch_bounds__(256) void flash_mfma(const u16* __restrict__ Q,
                                                  const u16* __restrict__ K,
                                                  const u16* __restrict__ Vt,
                                                  u16* __restrict__ O) {
    __shared__ u16 Ks[64 * 128];      // [kp][d], granule-XOR-swizzled by kp&15
    __shared__ u16 Vs[128 * 64];      // [d][kp], granule-XOR-swizzled by d&7
    __shared__ u16 Ps[4][32 * 72];    // per-wave P [q][kp], stride 72
    __shared__ float als[4][32];
    __shared__ float lls[4][32];
    const int tid  = threadIdx.x;
    const int lane = tid & 63, w = tid >> 6;
    const int l15  = lane & 15, quad = lane >> 4;

    // head-affine XCD remap: XCD x (= id&7) handles heads 8x..8x+7
    const int id  = blockIdx.x;                // 512 blocks
    const int bh  = (id & 7) * 8 + ((id >> 3) & 7);
    const int bxp = id >> 6;                   // 0..7 pairing slot

    // staging pointers (wave w owns chunks 4w..4w+3 of each buffer); bh-only
    const u16* Kg[4]; const u16* Vg[4];
    u16* KsD[4]; u16* VsD[4];
#pragma unroll
    for (int cc = 0; cc < 4; cc++) {
        int kp = w * 16 + cc * 4 + quad;
        int gs = l15 ^ (cc * 4 + quad);
        Kg[cc]  = K + ((size_t)bh * Tt + kp) * Dd + gs * 8;
        KsD[cc] = Ks + (w * 4 + cc) * 512;
        int d  = w * 32 + cc * 8 + (lane >> 3);
        int gv = (lane & 7) ^ (lane >> 3);
        Vg[cc]  = Vt + ((size_t)bh * Dd + d) * Tt + gv * 8;
        VsD[cc] = Vs + (w * 4 + cc) * 512;
    }

    const f32x4 zero4 = {0.f, 0.f, 0.f, 0.f};

    for (int ph = 0; ph < 2; ph++) {
        const int qt = ph ? bxp : 15 - bxp;
        const int q0 = qt * 128;

        // Q fragments (B-operand of S^T): q=nt*16+l15, d=ks*32+quad*8
        short8 qf[2][4];
        const u16* Qb = Q + ((size_t)bh * Tt + q0 + w * 32 + l15) * Dd + quad * 8;
#pragma unroll
        for (int nt = 0; nt < 2; nt++)
#pragma unroll
            for (int ks = 0; ks < 4; ks++)
                qf[nt][ks] = *(const short8*)(Qb + nt * 16 * Dd + ks * 32);

        f32x4 Oa[2][8];
#pragma unroll
        for (int mo = 0; mo < 2; mo++)
#pragma unroll
            for (int nt2 = 0; nt2 < 8; nt2++) Oa[mo][nt2] = zero4;
        float mrow[2] = {-INFINITY, -INFINITY};
        float lrow[2] = {0.f, 0.f};

        const int nkt = 2 * qt + 2;
        for (int kt = 0; kt < nkt; kt++) {
            __syncthreads();
#pragma unroll
            for (int cc = 0; cc < 4; cc++) gl_lds16(Kg[cc] + (size_t)kt * 64 * Dd, KsD[cc]);
#pragma unroll
            for (int cc = 0; cc < 4; cc++) gl_lds16(Vg[cc] + kt * 64, VsD[cc]);
            __syncthreads();

            // wave-level skip: tile fully masked for this wave's 32 q-rows
            if (kt * 64 > q0 + w * 32 + 31) continue;  // barriers already done

            // S^T = K * Q^T : rows kp = mt*16+quad*4+r, cols q = nt*16+l15
            f32x4 sc[4][2];
#pragma unroll
            for (int mt = 0; mt < 4; mt++) { sc[mt][0] = zero4; sc[mt][1] = zero4; }
            __builtin_amdgcn_s_setprio(1);
#pragma unroll
            for (int ks = 0; ks < 4; ks++) {
                short8 kf[4];
#pragma unroll
                for (int mt = 0; mt < 4; mt++)
                    kf[mt] = *(const short8*)(Ks + (mt * 16 + l15) * 128 +
                                              (((ks * 4 + quad) ^ l15) * 8));
#pragma unroll
                for (int mt = 0; mt < 4; mt++) {
                    sc[mt][0] = __builtin_amdgcn_mfma_f32_16x16x32_bf16(kf[mt], qf[0][ks], sc[mt][0], 0, 0, 0);
                    sc[mt][1] = __builtin_amdgcn_mfma_f32_16x16x32_bf16(kf[mt], qf[1][ks], sc[mt][1], 0, 0, 0);
                }
            }
            __builtin_amdgcn_s_setprio(0);

            const bool diag = (kt * 64 + 63 > q0 + w * 32);
            // online softmax in exp2 domain (scale*log2e pre-folded into Q)
#pragma unroll
            for (int nt = 0; nt < 2; nt++) {
                const int q_g = q0 + w * 32 + nt * 16 + l15;
                float sv[16];
#pragma unroll
                for (int mt = 0; mt < 4; mt++)
#pragma unroll
                    for (int r = 0; r < 4; r++)
                        sv[mt * 4 + r] = sc[mt][nt][r];
                if (diag) {
#pragma unroll
                    for (int mt = 0; mt < 4; mt++)
#pragma unroll
                        for (int r = 0; r < 4; r++) {
                            int kp_g = kt * 64 + mt * 16 + quad * 4 + r;
                            if (kp_g > q_g) sv[mt * 4 + r] = -INFINITY;
                        }
                }
                // tree max (depth 4)
                float m8[8], m4[4];
#pragma unroll
                for (int e = 0; e < 8; e++) m8[e] = fmaxf(sv[e], sv[e + 8]);
#pragma unroll
                for (int e = 0; e < 4; e++) m4[e] = fmaxf(m8[e], m8[e + 4]);
                float mx = fmaxf(fmaxf(m4[0], m4[1]), fmaxf(m4[2], m4[3]));
                mx = fmaxf(mx, __shfl_xor(mx, 16, 64));
                mx = fmaxf(mx, __shfl_xor(mx, 32, 64));
                float mnew = fmaxf(mrow[nt], mx);
                // defer-max (T13): keep old running max when growth <= 8
                mnew = (mnew - mrow[nt] <= 8.f) ? mrow[nt] : mnew;
                float alpha = exp2f(mrow[nt] - mnew);
                float pv[16];
#pragma unroll
                for (int e = 0; e < 16; e++) pv[e] = exp2f(sv[e] - mnew);
                // tree sum (depth 4)
                float s8[8], s4[4];
#pragma unroll
                for (int e = 0; e < 8; e++) s8[e] = pv[e] + pv[e + 8];
#pragma unroll
                for (int e = 0; e < 4; e++) s4[e] = s8[e] + s8[e + 4];
                float rs = (s4[0] + s4[1]) + (s4[2] + s4[3]);
                rs += __shfl_xor(rs, 16, 64);
                rs += __shfl_xor(rs, 32, 64);
                lrow[nt] = lrow[nt] * alpha + rs;
                mrow[nt] = mnew;
                if (quad == 0) als[w][nt * 16 + l15] = alpha;
#pragma unroll
                for (int mt = 0; mt < 4; mt++) {
                    union { ushort4 u; u16 s[4]; } pk;
#pragma unroll
                    for (int r = 0; r < 4; r++) pk.s[r] = f2bf(pv[mt * 4 + r]);
                    *(ushort4*)&Ps[w][(nt * 16 + l15) * 72 + mt * 16 + quad * 4] = pk.u;
                }
            }

            // rescale O by alpha; wave-uniform skip when all alphas == 1
            float ao[2][4];
            bool need = false;
#pragma unroll
            for (int mo = 0; mo < 2; mo++)
#pragma unroll
                for (int r = 0; r < 4; r++) {
                    ao[mo][r] = als[w][mo * 16 + quad * 4 + r];
                    need |= (ao[mo][r] != 1.f);
                }
            if (__any(need)) {
#pragma unroll
                for (int mo = 0; mo < 2; mo++)
#pragma unroll
                    for (int nt2 = 0; nt2 < 8; nt2++)
#pragma unroll
                        for (int r = 0; r < 4; r++) Oa[mo][nt2][r] *= ao[mo][r];
            }

            // O += P * V
            __builtin_amdgcn_s_setprio(1);
#pragma unroll
            for (int ks2 = 0; ks2 < 2; ks2++) {
                short8 pf[2];
#pragma unroll
                for (int mo = 0; mo < 2; mo++)
                    pf[mo] = *(const short8*)&Ps[w][(mo * 16 + l15) * 72 + ks2 * 32 + quad * 8];
#pragma unroll
                for (int nt2 = 0; nt2 < 8; nt2++) {
                    short8 vf = *(const short8*)(Vs + (nt2 * 16 + l15) * 64 +
                                                 (((ks2 * 4 + quad) ^ (l15 & 7)) * 8));
                    Oa[0][nt2] = __builtin_amdgcn_mfma_f32_16x16x32_bf16(pf[0], vf, Oa[0][nt2], 0, 0, 0);
                    Oa[1][nt2] = __builtin_amdgcn_mfma_f32_16x16x32_bf16(pf[1], vf, Oa[1][nt2], 0, 0, 0);
                }
            }
            __builtin_amdgcn_s_setprio(0);
        }

        // epilogue: normalize by l, store bf16 (B,T,ATTN)
        if (quad == 0) { lls[w][l15] = lrow[0]; lls[w][16 + l15] = lrow[1]; }
        float li[2][4];
#pragma unroll
        for (int mo = 0; mo < 2; mo++)
#pragma unroll
            for (int r = 0; r < 4; r++) li[mo][r] = 1.f / lls[w][mo * 16 + quad * 4 + r];
        const int b = bh >> 4, h = bh & 15;
#pragma unroll
        for (int mo = 0; mo < 2; mo++)
#pragma unroll
            for (int r = 0; r < 4; r++) {
                size_t ro = ((size_t)b * Tt + q0 + w * 32 + mo * 16 + quad * 4 + r) * ATTN
                            + h * Dd;
#pragma unroll
                for (int nt2 = 0; nt2 < 8; nt2++)
                    O[ro + nt2 * 16 + l15] = f2bf(Oa[mo][nt2][r] * li[mo][r]);
            }
    }
}

extern "C" void kernel_launch(void* const* d_in, const int* in_sizes, int n_in,
                              void* d_out, int out_size, void* d_ws, size_t ws_size,
                              hipStream_t stream) {
    const float* x    = (const float*)d_in[0];
    const float* wq_w = (const float*)d_in[3];
    const float* wq_b = (const float*)d_in[4];
    const float* wk_w = (const float*)d_in[5];
    const float* wk_b = (const float*)d_in[6];
    const float* wv_w = (const float*)d_in[7];
    const float* wv_b = (const float*)d_in[8];
    const float* wo_w = (const float*)d_in[9];
    const float* wo_b = (const float*)d_in[10];

    char* ws = (char*)d_ws;
    u16*   qb  = (u16*)(ws);                    // 32 MiB bf16 (B,H,T,D)
    u16*   kb  = (u16*)(ws + 33554432);         // 32 MiB bf16 (B,H,T,D)
    u16*   vtb = (u16*)(ws + 67108864);         // 32 MiB bf16 (B,H,D,T)
    u16*   xb  = (u16*)(ws + 100663296);        // 32 MiB bf16 x (8192x2048)
    u16*   obb = xb;                            // flash out aliases xb (x dead)
    u16*   wqb = (u16*)(ws + 134217728);        // 8 MiB each
    u16*   wkb = (u16*)(ws + 142606336);
    u16*   wvb = (u16*)(ws + 150994944);
    u16*   wob = (u16*)(ws + 159383552);
    float* ct  = (float*)(ws + 167772160);      // 512 KiB
    float* st  = (float*)(ws + 168296448);      // 512 KiB

    freq_kernel<<<512, 256, 0, stream>>>(ct, st);
    cvt_kernel<<<16384, 256, 0, stream>>>(x, xb, 4194304);
    cvt_kernel<<<4096, 256, 0, stream>>>(wq_w, wqb, 1048576);
    cvt_kernel<<<4096, 256, 0, stream>>>(wk_w, wkb, 1048576);
    cvt_kernel<<<4096, 256, 0, stream>>>(wv_w, wvb, 1048576);
    cvt_kernel<<<4096, 256, 0, stream>>>(wo_w, wob, 1048576);

    gemm_mfma<1><<<256, 512, 131072, stream>>>(xb, wqb, wq_b, qb);
    gemm_mfma<1><<<256, 512, 131072, stream>>>(xb, wkb, wk_b, kb);
    gemm_mfma<2><<<256, 512, 131072, stream>>>(xb, wvb, wv_b, vtb);
    rope_kernel<<<8192, 256, 0, stream>>>(qb, kb, ct, st);
    flash_mfma<<<512, 256, 0, stream>>>(qb, kb, vtb, obb);
    gemm_mfma<0><<<256, 512, 131072, stream>>>(obb, wob, wo_b, (float*)d_out);
}

// Round 9
// 637.003 us; speedup vs baseline: 1.0435x; 1.0329x over previous
//
#include <hip/hip_runtime.h>
#include <math.h>

#define Tt 2048
#define Hh 16
#define Dd 128
#define ATTN 2048
#define QSCALE 0.12751743f   // 1/sqrt(128) * log2(e), folded into q at epilogue

typedef unsigned short u16;
typedef __attribute__((ext_vector_type(8))) short short8;
typedef __attribute__((ext_vector_type(4))) float f32x4;

__device__ __forceinline__ float bf2f(u16 h) {
    union { unsigned int u; float f; } x;
    x.u = ((unsigned int)h) << 16;
    return x.f;
}
__device__ __forceinline__ u16 f2bf(float f) {
    union { float f; unsigned int u; } x;
    x.f = f;
    unsigned int r = x.u + 0x7fffu + ((x.u >> 16) & 1u);  // RNE
    return (u16)(r >> 16);
}
// async global->LDS, 16B per lane; lptr is wave-uniform base, HW adds lane*16.
__device__ __forceinline__ void gl_lds16(const void* g, void* l) {
    __builtin_amdgcn_global_load_lds(
        (const __attribute__((address_space(1))) unsigned int*)g,
        (__attribute__((address_space(3))) unsigned int*)l, 16, 0, 0);
}

// ---- RoPE cos/sin table (reference ignores freqs_cos/sin inputs; recompute).
__global__ __launch_bounds__(256) void freq_kernel(float* __restrict__ cost,
                                                   float* __restrict__ sint) {
    int idx = blockIdx.x * 256 + threadIdx.x;   // Tt*64
    if (idx >= Tt * 64) return;
    int t = idx >> 6, i = idx & 63;
    double inv = exp(-((double)(2 * i) / 128.0) * log(10000.0));
    double ang = (double)t * inv;
    cost[idx] = (float)cos(ang);
    sint[idx] = (float)sin(ang);
}

// ---- fp32 -> bf16 bulk convert (vectorized), n4 = elems/4
__global__ __launch_bounds__(256) void cvt_kernel(const float* __restrict__ in,
                                                  u16* __restrict__ out, int n4) {
    int i = blockIdx.x * 256 + threadIdx.x;
    if (i >= n4) return;
    float4 v = *(const float4*)(in + (size_t)i * 4);
    union { ushort4 u; u16 s[4]; } pk;
    pk.s[0] = f2bf(v.x); pk.s[1] = f2bf(v.y);
    pk.s[2] = f2bf(v.z); pk.s[3] = f2bf(v.w);
    *(ushort4*)(out + (size_t)i * 4) = pk.u;
}

// ---- 4 weight matrices fp32->bf16 in one launch (gridDim.y selects)
__global__ __launch_bounds__(256) void cvtw_kernel(const float* __restrict__ w0,
                                                   const float* __restrict__ w1,
                                                   const float* __restrict__ w2,
                                                   const float* __restrict__ w3,
                                                   u16* __restrict__ o0,
                                                   u16* __restrict__ o1,
                                                   u16* __restrict__ o2,
                                                   u16* __restrict__ o3) {
    int i = blockIdx.x * 256 + threadIdx.x;      // 1048576 float4 groups each
    const float* in; u16* out;
    switch (blockIdx.y) {
        case 0:  in = w0; out = o0; break;
        case 1:  in = w1; out = o1; break;
        case 2:  in = w2; out = o2; break;
        default: in = w3; out = o3; break;
    }
    float4 v = *(const float4*)(in + (size_t)i * 4);
    union { ushort4 u; u16 s[4]; } pk;
    pk.s[0] = f2bf(v.x); pk.s[1] = f2bf(v.y);
    pk.s[2] = f2bf(v.z); pk.s[3] = f2bf(v.w);
    *(ushort4*)(out + (size_t)i * 4) = pk.u;
}

// ---- bf16 MFMA GEMM, 256x256 tile, BK=64, 8 waves (512 thr, 2Mx4N grid).
// Fine-phase schedule (R8): 4 phases/K-tile, 16 MFMA each, counted staging.
// R9: RoPE FUSED into q/k epilogues -- rope pairs (2i,2i+1) are adjacent d
// = adjacent l15 lanes, so one __shfl_xor(v,1) + fma rotates in-register
// (and on f32 pre-rounding values: single bf16 round, closer to reference).
// Kills the rope_kernel's 128 MiB q/k HBM round-trip.
// MODE 0: fp32 (M,2048). MODE 2: bf16 V^T (B,H,D,T).
// MODE 3: bf16 (B,H,T,D) + rope + QSCALE (q). MODE 4: + rope (k).
template<int MODE>
__global__ __launch_bounds__(512, 2) void gemm_mfma(const u16* __restrict__ A,
                                                    const u16* __restrict__ W,
                                                    const float* __restrict__ bias,
                                                    void* __restrict__ Cout,
                                                    const float* __restrict__ ct,
                                                    const float* __restrict__ st) {
    extern __shared__ u16 lds[];   // 131072 B: [buf2][A0,A1,B0,B1][8192 u16]
    const int tid  = threadIdx.x;
    const int lane = tid & 63, w = tid >> 6;       // 8 waves
    const int l15  = lane & 15, quad = lane >> 4;
    const int wm = w >> 2, wn = w & 3;             // 2 x 4 wave grid

    const int id = blockIdx.x;                     // 256 blocks = 1/CU
    const int bx = id & 7, by = id >> 3;           // XCD id&7 owns B-panel bx
    const int m0 = by * 256, n0 = bx * 256;

    const f32x4 zero4 = {0.f, 0.f, 0.f, 0.f};
    f32x4 acc[8][4];
#pragma unroll
    for (int mt = 0; mt < 8; mt++)
#pragma unroll
        for (int nt = 0; nt < 4; nt++) acc[mt][nt] = zero4;

    // staging: thread covers row (w*16 + j*8 + lane>>3) of a 128-row half,
    // physical chunk lane&7 carries global chunk (lane&7)^(lane>>3).
    const int srow = w * 16 + (lane >> 3);
    const int gsc  = ((lane & 7) ^ (lane >> 3)) * 8;
    const u16* Ag = A + (size_t)(m0 + srow) * 2048 + gsc;
    const u16* Wg = W + (size_t)(n0 + srow) * 2048 + gsc;
    const int wB = w * 1024;                       // wave's j=0 dest (elems)

    // read-side offsets (elems): chunk = (ks*4+quad)^(row&7), row&7 == l15&7
    const int s7 = l15 & 7;
    const int cA = wm * 8192 + l15 * 64;                              // +mt*1024
    const int cB = 16384 + (wn >> 1) * 8192 + ((wn & 1) * 64 + l15) * 64;  // +nt*1024
    const int ck0 = (quad ^ s7) * 8;
    const int ck1 = ((quad ^ s7) ^ 4) * 8;

#define STAGE(tt, dd, ss) do { \
    const u16* _g = (((ss) < 2) ? Ag : Wg) + (((ss) & 1) ? (size_t)(128 * 2048) : (size_t)0) \
                    + (size_t)(tt) * 64; \
    u16* _l = lds + (dd) * 32768 + (ss) * 8192 + wB; \
    gl_lds16(_g, _l); \
    gl_lds16(_g + (size_t)8 * 2048, _l + 512); \
} while (0)

    // prologue: full tile0 -> buf0 (8 loads in flight)
    STAGE(0, 0, 0); STAGE(0, 0, 1); STAGE(0, 0, 2); STAGE(0, 0, 3);

    short8 afQ[4], bfr[4][2];
    for (int t = 0; t < 32; t++) {
        const int d = t & 1, e = d ^ 1;
        const u16* bufd = lds + d * 32768;
        const bool pf = (t + 1 < 32);

        // entry: tile t's 8 loads landed (issued one full tile ago)
        asm volatile("s_waitcnt vmcnt(0)" ::: "memory");
        __builtin_amdgcn_sched_barrier(0);
        __builtin_amdgcn_s_barrier();
        __builtin_amdgcn_sched_barrier(0);

        // ---- phase 1: read Q1 (af mt0-3 kx0, bf kx0); stage A(t+1)->buf e
#pragma unroll
        for (int i = 0; i < 4; i++)
            afQ[i] = *(const short8*)(bufd + cA + i * 1024 + ck0);
#pragma unroll
        for (int i = 0; i < 4; i++)
            bfr[i][0] = *(const short8*)(bufd + cB + i * 1024 + ck0);
        if (pf) { STAGE(t + 1, e, 0); STAGE(t + 1, e, 1); }
        __builtin_amdgcn_sched_barrier(0);
        __builtin_amdgcn_s_barrier();
        asm volatile("s_waitcnt lgkmcnt(0)" ::: "memory");
        __builtin_amdgcn_sched_barrier(0);
        __builtin_amdgcn_s_setprio(1);
#pragma unroll
        for (int i = 0; i < 4; i++)
#pragma unroll
            for (int j = 0; j < 4; j++)
                acc[i][j] = __builtin_amdgcn_mfma_f32_16x16x32_bf16(
                    afQ[i], bfr[j][0], acc[i][j], 0, 0, 0);
        __builtin_amdgcn_s_setprio(0);
        __builtin_amdgcn_sched_barrier(0);
        __builtin_amdgcn_s_barrier();
        __builtin_amdgcn_sched_barrier(0);

        // ---- phase 2: read af mt4-7 kx0; stage B-h0(t+1)
#pragma unroll
        for (int i = 0; i < 4; i++)
            afQ[i] = *(const short8*)(bufd + cA + (i + 4) * 1024 + ck0);
        if (pf) STAGE(t + 1, e, 2);
        __builtin_amdgcn_sched_barrier(0);
        __builtin_amdgcn_s_barrier();
        asm volatile("s_waitcnt lgkmcnt(0)" ::: "memory");
        __builtin_amdgcn_sched_barrier(0);
        __builtin_amdgcn_s_setprio(1);
#pragma unroll
        for (int i = 0; i < 4; i++)
#pragma unroll
            for (int j = 0; j < 4; j++)
                acc[i + 4][j] = __builtin_amdgcn_mfma_f32_16x16x32_bf16(
                    afQ[i], bfr[j][0], acc[i + 4][j], 0, 0, 0);
        __builtin_amdgcn_s_setprio(0);
        __builtin_amdgcn_sched_barrier(0);
        __builtin_amdgcn_s_barrier();
        __builtin_amdgcn_sched_barrier(0);

        // ---- phase 3: read Q3 (af mt0-3 kx1, bf kx1); stage B-h1(t+1)
#pragma unroll
        for (int i = 0; i < 4; i++)
            afQ[i] = *(const short8*)(bufd + cA + i * 1024 + ck1);
#pragma unroll
        for (int i = 0; i < 4; i++)
            bfr[i][1] = *(const short8*)(bufd + cB + i * 1024 + ck1);
        if (pf) STAGE(t + 1, e, 3);
        __builtin_amdgcn_sched_barrier(0);
        __builtin_amdgcn_s_barrier();
        asm volatile("s_waitcnt lgkmcnt(0)" ::: "memory");
        __builtin_amdgcn_sched_barrier(0);
        __builtin_amdgcn_s_setprio(1);
#pragma unroll
        for (int i = 0; i < 4; i++)
#pragma unroll
            for (int j = 0; j < 4; j++)
                acc[i][j] = __builtin_amdgcn_mfma_f32_16x16x32_bf16(
                    afQ[i], bfr[j][1], acc[i][j], 0, 0, 0);
        __builtin_amdgcn_s_setprio(0);
        __builtin_amdgcn_sched_barrier(0);
        __builtin_amdgcn_s_barrier();
        __builtin_amdgcn_sched_barrier(0);

        // ---- phase 4: read af mt4-7 kx1
#pragma unroll
        for (int i = 0; i < 4; i++)
            afQ[i] = *(const short8*)(bufd + cA + (i + 4) * 1024 + ck1);
        __builtin_amdgcn_sched_barrier(0);
        __builtin_amdgcn_s_barrier();
        asm volatile("s_waitcnt lgkmcnt(0)" ::: "memory");
        __builtin_amdgcn_sched_barrier(0);
        __builtin_amdgcn_s_setprio(1);
#pragma unroll
        for (int i = 0; i < 4; i++)
#pragma unroll
            for (int j = 0; j < 4; j++)
                acc[i + 4][j] = __builtin_amdgcn_mfma_f32_16x16x32_bf16(
                    afQ[i], bfr[j][1], acc[i + 4][j], 0, 0, 0);
        __builtin_amdgcn_s_setprio(0);
        __builtin_amdgcn_sched_barrier(0);
        __builtin_amdgcn_s_barrier();
        __builtin_amdgcn_sched_barrier(0);
    }
#undef STAGE

    float bn[4];
#pragma unroll
    for (int nt = 0; nt < 4; nt++) bn[nt] = bias[n0 + wn * 64 + nt * 16 + l15];

    if (MODE == 0) {
        float* C = (float*)Cout;
#pragma unroll
        for (int mt = 0; mt < 8; mt++) {
            int m = m0 + wm * 128 + mt * 16 + quad * 4;
#pragma unroll
            for (int nt = 0; nt < 4; nt++) {
                int n = n0 + wn * 64 + nt * 16 + l15;
#pragma unroll
                for (int r = 0; r < 4; r++)
                    C[(size_t)(m + r) * 2048 + n] = acc[mt][nt][r] + bn[nt];
            }
        }
    } else if (MODE == 3 || MODE == 4) {
        // bf16 (B,H,T,D) + fused RoPE (pair partner = lane^1 via shfl_xor)
        u16* C = (u16*)Cout;
#pragma unroll
        for (int mt = 0; mt < 8; mt++) {
            int m = m0 + wm * 128 + mt * 16 + quad * 4;
            int b = m >> 11, tr = m & 2047;
#pragma unroll
            for (int nt = 0; nt < 4; nt++) {
                int n = n0 + wn * 64 + nt * 16 + l15;
                int h = n >> 7, dd = n & 127;
                size_t base = ((size_t)(b * Hh + h) * Tt + tr) * Dd + dd;
#pragma unroll
                for (int r = 0; r < 4; r++) {
                    float v = acc[mt][nt][r] + bn[nt];
                    float other = __shfl_xor(v, 1, 64);
                    float c = ct[(tr + r) * 64 + (dd >> 1)];
                    float s = st[(tr + r) * 64 + (dd >> 1)];
                    // even d holds q0: q0*c - q1*s ; odd d holds q1: q0*s + q1*c
                    float rot = (dd & 1) ? (other * s + v * c)
                                         : (v * c - other * s);
                    if (MODE == 3) rot *= QSCALE;
                    C[base + (size_t)r * Dd] = f2bf(rot);
                }
            }
        }
    } else {  // MODE 2: V transposed (B,H,D,T), pack 4 consecutive t per lane
        u16* C = (u16*)Cout;
        const int b = m0 >> 11;
#pragma unroll
        for (int mt = 0; mt < 8; mt++) {
            int tloc = (m0 & 2047) + wm * 128 + mt * 16 + quad * 4;
#pragma unroll
            for (int nt = 0; nt < 4; nt++) {
                int n = n0 + wn * 64 + nt * 16 + l15;
                int h = n >> 7, dd = n & 127;
                union { ushort4 u; u16 s[4]; } pk;
#pragma unroll
                for (int r = 0; r < 4; r++) pk.s[r] = f2bf(acc[mt][nt][r] + bn[nt]);
                *(ushort4*)&C[((size_t)(b * Hh + h) * Dd + dd) * Tt + tloc] = pk.u;
            }
        }
    }
}

// ---- MFMA flash attention (causal), R5 structure (measured 211us): R0
// double-barrier staging + head-affine XCD remap + T5 setprio + tree
// reductions + defer-max. UNCHANGED this round.
__global__ __launch_bounds__(256) void flash_mfma(const u16* __restrict__ Q,
                                                  const u16* __restrict__ K,
                                                  const u16* __restrict__ Vt,
                                                  u16* __restrict__ O) {
    __shared__ u16 Ks[64 * 128];      // [kp][d], granule-XOR-swizzled by kp&15
    __shared__ u16 Vs[128 * 64];      // [d][kp], granule-XOR-swizzled by d&7
    __shared__ u16 Ps[4][32 * 72];    // per-wave P [q][kp], stride 72
    __shared__ float als[4][32];
    __shared__ float lls[4][32];
    const int tid  = threadIdx.x;
    const int lane = tid & 63, w = tid >> 6;
    const int l15  = lane & 15, quad = lane >> 4;

    // head-affine XCD remap: XCD x (= id&7) handles heads 8x..8x+7
    const int id  = blockIdx.x;                // 512 blocks
    const int bh  = (id & 7) * 8 + ((id >> 3) & 7);
    const int bxp = id >> 6;                   // 0..7 pairing slot

    // staging pointers (wave w owns chunks 4w..4w+3 of each buffer); bh-only
    const u16* Kg[4]; const u16* Vg[4];
    u16* KsD[4]; u16* VsD[4];
#pragma unroll
    for (int cc = 0; cc < 4; cc++) {
        int kp = w * 16 + cc * 4 + quad;
        int gs = l15 ^ (cc * 4 + quad);
        Kg[cc]  = K + ((size_t)bh * Tt + kp) * Dd + gs * 8;
        KsD[cc] = Ks + (w * 4 + cc) * 512;
        int d  = w * 32 + cc * 8 + (lane >> 3);
        int gv = (lane & 7) ^ (lane >> 3);
        Vg[cc]  = Vt + ((size_t)bh * Dd + d) * Tt + gv * 8;
        VsD[cc] = Vs + (w * 4 + cc) * 512;
    }

    const f32x4 zero4 = {0.f, 0.f, 0.f, 0.f};

    for (int ph = 0; ph < 2; ph++) {
        const int qt = ph ? bxp : 15 - bxp;
        const int q0 = qt * 128;

        // Q fragments (B-operand of S^T): q=nt*16+l15, d=ks*32+quad*8
        short8 qf[2][4];
        const u16* Qb = Q + ((size_t)bh * Tt + q0 + w * 32 + l15) * Dd + quad * 8;
#pragma unroll
        for (int nt = 0; nt < 2; nt++)
#pragma unroll
            for (int ks = 0; ks < 4; ks++)
                qf[nt][ks] = *(const short8*)(Qb + nt * 16 * Dd + ks * 32);

        f32x4 Oa[2][8];
#pragma unroll
        for (int mo = 0; mo < 2; mo++)
#pragma unroll
            for (int nt2 = 0; nt2 < 8; nt2++) Oa[mo][nt2] = zero4;
        float mrow[2] = {-INFINITY, -INFINITY};
        float lrow[2] = {0.f, 0.f};

        const int nkt = 2 * qt + 2;
        for (int kt = 0; kt < nkt; kt++) {
            __syncthreads();
#pragma unroll
            for (int cc = 0; cc < 4; cc++) gl_lds16(Kg[cc] + (size_t)kt * 64 * Dd, KsD[cc]);
#pragma unroll
            for (int cc = 0; cc < 4; cc++) gl_lds16(Vg[cc] + kt * 64, VsD[cc]);
            __syncthreads();

            // wave-level skip: tile fully masked for this wave's 32 q-rows
            if (kt * 64 > q0 + w * 32 + 31) continue;  // barriers already done

            // S^T = K * Q^T : rows kp = mt*16+quad*4+r, cols q = nt*16+l15
            f32x4 sc[4][2];
#pragma unroll
            for (int mt = 0; mt < 4; mt++) { sc[mt][0] = zero4; sc[mt][1] = zero4; }
            __builtin_amdgcn_s_setprio(1);
#pragma unroll
            for (int ks = 0; ks < 4; ks++) {
                short8 kf[4];
#pragma unroll
                for (int mt = 0; mt < 4; mt++)
                    kf[mt] = *(const short8*)(Ks + (mt * 16 + l15) * 128 +
                                              (((ks * 4 + quad) ^ l15) * 8));
#pragma unroll
                for (int mt = 0; mt < 4; mt++) {
                    sc[mt][0] = __builtin_amdgcn_mfma_f32_16x16x32_bf16(kf[mt], qf[0][ks], sc[mt][0], 0, 0, 0);
                    sc[mt][1] = __builtin_amdgcn_mfma_f32_16x16x32_bf16(kf[mt], qf[1][ks], sc[mt][1], 0, 0, 0);
                }
            }
            __builtin_amdgcn_s_setprio(0);

            const bool diag = (kt * 64 + 63 > q0 + w * 32);
            // online softmax in exp2 domain (scale*log2e pre-folded into Q)
#pragma unroll
            for (int nt = 0; nt < 2; nt++) {
                const int q_g = q0 + w * 32 + nt * 16 + l15;
                float sv[16];
#pragma unroll
                for (int mt = 0; mt < 4; mt++)
#pragma unroll
                    for (int r = 0; r < 4; r++)
                        sv[mt * 4 + r] = sc[mt][nt][r];
                if (diag) {
#pragma unroll
                    for (int mt = 0; mt < 4; mt++)
#pragma unroll
                        for (int r = 0; r < 4; r++) {
                            int kp_g = kt * 64 + mt * 16 + quad * 4 + r;
                            if (kp_g > q_g) sv[mt * 4 + r] = -INFINITY;
                        }
                }
                // tree max (depth 4)
                float m8[8], m4[4];
#pragma unroll
                for (int e = 0; e < 8; e++) m8[e] = fmaxf(sv[e], sv[e + 8]);
#pragma unroll
                for (int e = 0; e < 4; e++) m4[e] = fmaxf(m8[e], m8[e + 4]);
                float mx = fmaxf(fmaxf(m4[0], m4[1]), fmaxf(m4[2], m4[3]));
                mx = fmaxf(mx, __shfl_xor(mx, 16, 64));
                mx = fmaxf(mx, __shfl_xor(mx, 32, 64));
                float mnew = fmaxf(mrow[nt], mx);
                // defer-max (T13): keep old running max when growth <= 8
                mnew = (mnew - mrow[nt] <= 8.f) ? mrow[nt] : mnew;
                float alpha = exp2f(mrow[nt] - mnew);
                float pv[16];
#pragma unroll
                for (int e = 0; e < 16; e++) pv[e] = exp2f(sv[e] - mnew);
                // tree sum (depth 4)
                float s8[8], s4[4];
#pragma unroll
                for (int e = 0; e < 8; e++) s8[e] = pv[e] + pv[e + 8];
#pragma unroll
                for (int e = 0; e < 4; e++) s4[e] = s8[e] + s8[e + 4];
                float rs = (s4[0] + s4[1]) + (s4[2] + s4[3]);
                rs += __shfl_xor(rs, 16, 64);
                rs += __shfl_xor(rs, 32, 64);
                lrow[nt] = lrow[nt] * alpha + rs;
                mrow[nt] = mnew;
                if (quad == 0) als[w][nt * 16 + l15] = alpha;
#pragma unroll
                for (int mt = 0; mt < 4; mt++) {
                    union { ushort4 u; u16 s[4]; } pk;
#pragma unroll
                    for (int r = 0; r < 4; r++) pk.s[r] = f2bf(pv[mt * 4 + r]);
                    *(ushort4*)&Ps[w][(nt * 16 + l15) * 72 + mt * 16 + quad * 4] = pk.u;
                }
            }

            // rescale O by alpha; wave-uniform skip when all alphas == 1
            float ao[2][4];
            bool need = false;
#pragma unroll
            for (int mo = 0; mo < 2; mo++)
#pragma unroll
                for (int r = 0; r < 4; r++) {
                    ao[mo][r] = als[w][mo * 16 + quad * 4 + r];
                    need |= (ao[mo][r] != 1.f);
                }
            if (__any(need)) {
#pragma unroll
                for (int mo = 0; mo < 2; mo++)
#pragma unroll
                    for (int nt2 = 0; nt2 < 8; nt2++)
#pragma unroll
                        for (int r = 0; r < 4; r++) Oa[mo][nt2][r] *= ao[mo][r];
            }

            // O += P * V
            __builtin_amdgcn_s_setprio(1);
#pragma unroll
            for (int ks2 = 0; ks2 < 2; ks2++) {
                short8 pf[2];
#pragma unroll
                for (int mo = 0; mo < 2; mo++)
                    pf[mo] = *(const short8*)&Ps[w][(mo * 16 + l15) * 72 + ks2 * 32 + quad * 8];
#pragma unroll
                for (int nt2 = 0; nt2 < 8; nt2++) {
                    short8 vf = *(const short8*)(Vs + (nt2 * 16 + l15) * 64 +
                                                 (((ks2 * 4 + quad) ^ (l15 & 7)) * 8));
                    Oa[0][nt2] = __builtin_amdgcn_mfma_f32_16x16x32_bf16(pf[0], vf, Oa[0][nt2], 0, 0, 0);
                    Oa[1][nt2] = __builtin_amdgcn_mfma_f32_16x16x32_bf16(pf[1], vf, Oa[1][nt2], 0, 0, 0);
                }
            }
            __builtin_amdgcn_s_setprio(0);
        }

        // epilogue: normalize by l, store bf16 (B,T,ATTN)
        if (quad == 0) { lls[w][l15] = lrow[0]; lls[w][16 + l15] = lrow[1]; }
        float li[2][4];
#pragma unroll
        for (int mo = 0; mo < 2; mo++)
#pragma unroll
            for (int r = 0; r < 4; r++) li[mo][r] = 1.f / lls[w][mo * 16 + quad * 4 + r];
        const int b = bh >> 4, h = bh & 15;
#pragma unroll
        for (int mo = 0; mo < 2; mo++)
#pragma unroll
            for (int r = 0; r < 4; r++) {
                size_t ro = ((size_t)b * Tt + q0 + w * 32 + mo * 16 + quad * 4 + r) * ATTN
                            + h * Dd;
#pragma unroll
                for (int nt2 = 0; nt2 < 8; nt2++)
                    O[ro + nt2 * 16 + l15] = f2bf(Oa[mo][nt2][r] * li[mo][r]);
            }
    }
}

extern "C" void kernel_launch(void* const* d_in, const int* in_sizes, int n_in,
                              void* d_out, int out_size, void* d_ws, size_t ws_size,
                              hipStream_t stream) {
    const float* x    = (const float*)d_in[0];
    const float* wq_w = (const float*)d_in[3];
    const float* wq_b = (const float*)d_in[4];
    const float* wk_w = (const float*)d_in[5];
    const float* wk_b = (const float*)d_in[6];
    const float* wv_w = (const float*)d_in[7];
    const float* wv_b = (const float*)d_in[8];
    const float* wo_w = (const float*)d_in[9];
    const float* wo_b = (const float*)d_in[10];

    char* ws = (char*)d_ws;
    u16*   qb  = (u16*)(ws);                    // 32 MiB bf16 (B,H,T,D)
    u16*   kb  = (u16*)(ws + 33554432);         // 32 MiB bf16 (B,H,T,D)
    u16*   vtb = (u16*)(ws + 67108864);         // 32 MiB bf16 (B,H,D,T)
    u16*   xb  = (u16*)(ws + 100663296);        // 32 MiB bf16 x (8192x2048)
    u16*   obb = xb;                            // flash out aliases xb (x dead)
    u16*   wqb = (u16*)(ws + 134217728);        // 8 MiB each
    u16*   wkb = (u16*)(ws + 142606336);
    u16*   wvb = (u16*)(ws + 150994944);
    u16*   wob = (u16*)(ws + 159383552);
    float* ct  = (float*)(ws + 167772160);      // 512 KiB
    float* st  = (float*)(ws + 168296448);      // 512 KiB

    freq_kernel<<<512, 256, 0, stream>>>(ct, st);
    cvt_kernel<<<16384, 256, 0, stream>>>(x, xb, 4194304);
    cvtw_kernel<<<dim3(4096, 4), 256, 0, stream>>>(wq_w, wk_w, wv_w, wo_w,
                                                   wqb, wkb, wvb, wob);

    gemm_mfma<3><<<256, 512, 131072, stream>>>(xb, wqb, wq_b, qb, ct, st);
    gemm_mfma<4><<<256, 512, 131072, stream>>>(xb, wkb, wk_b, kb, ct, st);
    gemm_mfma<2><<<256, 512, 131072, stream>>>(xb, wvb, wv_b, vtb, ct, st);
    flash_mfma<<<512, 256, 0, stream>>>(qb, kb, vtb, obb);
    gemm_mfma<0><<<256, 512, 131072, stream>>>(obb, wob, wo_b, (float*)d_out, ct, st);
}

// Round 10
// 619.884 us; speedup vs baseline: 1.0723x; 1.0276x over previous
//
#include <hip/hip_runtime.h>
#include <math.h>

#define Tt 2048
#define Hh 16
#define Dd 128
#define ATTN 2048
#define QSCALE 0.12751743f   // 1/sqrt(128) * log2(e), folded into q at epilogue

typedef unsigned short u16;
typedef __attribute__((ext_vector_type(8))) short short8;
typedef __attribute__((ext_vector_type(4))) float f32x4;

__device__ __forceinline__ float bf2f(u16 h) {
    union { unsigned int u; float f; } x;
    x.u = ((unsigned int)h) << 16;
    return x.f;
}
__device__ __forceinline__ u16 f2bf(float f) {
    union { float f; unsigned int u; } x;
    x.f = f;
    unsigned int r = x.u + 0x7fffu + ((x.u >> 16) & 1u);  // RNE
    return (u16)(r >> 16);
}
// async global->LDS, 16B per lane; lptr is wave-uniform base, HW adds lane*16.
__device__ __forceinline__ void gl_lds16(const void* g, void* l) {
    __builtin_amdgcn_global_load_lds(
        (const __attribute__((address_space(1))) unsigned int*)g,
        (__attribute__((address_space(3))) unsigned int*)l, 16, 0, 0);
}

// ---- RoPE cos/sin table (reference ignores freqs_cos/sin inputs; recompute).
__global__ __launch_bounds__(256) void freq_kernel(float* __restrict__ cost,
                                                   float* __restrict__ sint) {
    int idx = blockIdx.x * 256 + threadIdx.x;   // Tt*64
    if (idx >= Tt * 64) return;
    int t = idx >> 6, i = idx & 63;
    double inv = exp(-((double)(2 * i) / 128.0) * log(10000.0));
    double ang = (double)t * inv;
    cost[idx] = (float)cos(ang);
    sint[idx] = (float)sin(ang);
}

// ---- fp32 -> bf16 bulk convert (vectorized), n4 = elems/4
__global__ __launch_bounds__(256) void cvt_kernel(const float* __restrict__ in,
                                                  u16* __restrict__ out, int n4) {
    int i = blockIdx.x * 256 + threadIdx.x;
    if (i >= n4) return;
    float4 v = *(const float4*)(in + (size_t)i * 4);
    union { ushort4 u; u16 s[4]; } pk;
    pk.s[0] = f2bf(v.x); pk.s[1] = f2bf(v.y);
    pk.s[2] = f2bf(v.z); pk.s[3] = f2bf(v.w);
    *(ushort4*)(out + (size_t)i * 4) = pk.u;
}

// ---- 4 weight matrices fp32->bf16 in one launch (gridDim.y selects)
__global__ __launch_bounds__(256) void cvtw_kernel(const float* __restrict__ w0,
                                                   const float* __restrict__ w1,
                                                   const float* __restrict__ w2,
                                                   const float* __restrict__ w3,
                                                   u16* __restrict__ o0,
                                                   u16* __restrict__ o1,
                                                   u16* __restrict__ o2,
                                                   u16* __restrict__ o3) {
    int i = blockIdx.x * 256 + threadIdx.x;      // 1048576 float4 groups each
    const float* in; u16* out;
    switch (blockIdx.y) {
        case 0:  in = w0; out = o0; break;
        case 1:  in = w1; out = o1; break;
        case 2:  in = w2; out = o2; break;
        default: in = w3; out = o3; break;
    }
    float4 v = *(const float4*)(in + (size_t)i * 4);
    union { ushort4 u; u16 s[4]; } pk;
    pk.s[0] = f2bf(v.x); pk.s[1] = f2bf(v.y);
    pk.s[2] = f2bf(v.z); pk.s[3] = f2bf(v.w);
    *(ushort4*)(out + (size_t)i * 4) = pk.u;
}

// ---- bf16 MFMA GEMM, 256x256 tile, BK=64, 8 waves (512 thr, 2Mx4N grid).
// Fine-phase schedule (R8): 4 phases/K-tile, 16 MFMA each, counted staging.
// R10: A-panel-affine XCD remap. Old bx=id&7 kept B (the SMALL operand)
// L2-local while the 8 blocks sharing an A-panel spread over 8 XCDs ->
// A (33.5 MB) re-fetched per XCD = ~256 MB cross-fabric traffic per GEMM.
// New: XCD x owns by in {4x..4x+3} -> A-panels L2-shared by 8 co-resident
// blocks (fetched once), B streamed 8 MB/XCD. Fabric ~264 -> ~97 MB.
// MODE 0: fp32 (M,2048). MODE 2: bf16 V^T (B,H,D,T).
// MODE 3: bf16 (B,H,T,D) + rope + QSCALE (q). MODE 4: + rope (k).
template<int MODE>
__global__ __launch_bounds__(512, 2) void gemm_mfma(const u16* __restrict__ A,
                                                    const u16* __restrict__ W,
                                                    const float* __restrict__ bias,
                                                    void* __restrict__ Cout,
                                                    const float* __restrict__ ct,
                                                    const float* __restrict__ st) {
    extern __shared__ u16 lds[];   // 131072 B: [buf2][A0,A1,B0,B1][8192 u16]
    const int tid  = threadIdx.x;
    const int lane = tid & 63, w = tid >> 6;       // 8 waves
    const int l15  = lane & 15, quad = lane >> 4;
    const int wm = w >> 2, wn = w & 3;             // 2 x 4 wave grid

    const int id = blockIdx.x;                     // 256 blocks = 1/CU
    const int xcd = id & 7, j = id >> 3;
    const int by = xcd * 4 + (j & 3);              // XCD owns 4 A-panels
    const int bx = j >> 2;
    const int m0 = by * 256, n0 = bx * 256;

    const f32x4 zero4 = {0.f, 0.f, 0.f, 0.f};
    f32x4 acc[8][4];
#pragma unroll
    for (int mt = 0; mt < 8; mt++)
#pragma unroll
        for (int nt = 0; nt < 4; nt++) acc[mt][nt] = zero4;

    // staging: thread covers row (w*16 + j*8 + lane>>3) of a 128-row half,
    // physical chunk lane&7 carries global chunk (lane&7)^(lane>>3).
    const int srow = w * 16 + (lane >> 3);
    const int gsc  = ((lane & 7) ^ (lane >> 3)) * 8;
    const u16* Ag = A + (size_t)(m0 + srow) * 2048 + gsc;
    const u16* Wg = W + (size_t)(n0 + srow) * 2048 + gsc;
    const int wB = w * 1024;                       // wave's j=0 dest (elems)

    // read-side offsets (elems): chunk = (ks*4+quad)^(row&7), row&7 == l15&7
    const int s7 = l15 & 7;
    const int cA = wm * 8192 + l15 * 64;                              // +mt*1024
    const int cB = 16384 + (wn >> 1) * 8192 + ((wn & 1) * 64 + l15) * 64;  // +nt*1024
    const int ck0 = (quad ^ s7) * 8;
    const int ck1 = ((quad ^ s7) ^ 4) * 8;

#define STAGE(tt, dd, ss) do { \
    const u16* _g = (((ss) < 2) ? Ag : Wg) + (((ss) & 1) ? (size_t)(128 * 2048) : (size_t)0) \
                    + (size_t)(tt) * 64; \
    u16* _l = lds + (dd) * 32768 + (ss) * 8192 + wB; \
    gl_lds16(_g, _l); \
    gl_lds16(_g + (size_t)8 * 2048, _l + 512); \
} while (0)

    // prologue: full tile0 -> buf0 (8 loads in flight)
    STAGE(0, 0, 0); STAGE(0, 0, 1); STAGE(0, 0, 2); STAGE(0, 0, 3);

    short8 afQ[4], bfr[4][2];
    for (int t = 0; t < 32; t++) {
        const int d = t & 1, e = d ^ 1;
        const u16* bufd = lds + d * 32768;
        const bool pf = (t + 1 < 32);

        // entry: tile t's 8 loads landed (issued one full tile ago)
        asm volatile("s_waitcnt vmcnt(0)" ::: "memory");
        __builtin_amdgcn_sched_barrier(0);
        __builtin_amdgcn_s_barrier();
        __builtin_amdgcn_sched_barrier(0);

        // ---- phase 1: read Q1 (af mt0-3 kx0, bf kx0); stage A(t+1)->buf e
#pragma unroll
        for (int i = 0; i < 4; i++)
            afQ[i] = *(const short8*)(bufd + cA + i * 1024 + ck0);
#pragma unroll
        for (int i = 0; i < 4; i++)
            bfr[i][0] = *(const short8*)(bufd + cB + i * 1024 + ck0);
        if (pf) { STAGE(t + 1, e, 0); STAGE(t + 1, e, 1); }
        __builtin_amdgcn_sched_barrier(0);
        __builtin_amdgcn_s_barrier();
        asm volatile("s_waitcnt lgkmcnt(0)" ::: "memory");
        __builtin_amdgcn_sched_barrier(0);
        __builtin_amdgcn_s_setprio(1);
#pragma unroll
        for (int i = 0; i < 4; i++)
#pragma unroll
            for (int j2 = 0; j2 < 4; j2++)
                acc[i][j2] = __builtin_amdgcn_mfma_f32_16x16x32_bf16(
                    afQ[i], bfr[j2][0], acc[i][j2], 0, 0, 0);
        __builtin_amdgcn_s_setprio(0);
        __builtin_amdgcn_sched_barrier(0);
        __builtin_amdgcn_s_barrier();
        __builtin_amdgcn_sched_barrier(0);

        // ---- phase 2: read af mt4-7 kx0; stage B-h0(t+1)
#pragma unroll
        for (int i = 0; i < 4; i++)
            afQ[i] = *(const short8*)(bufd + cA + (i + 4) * 1024 + ck0);
        if (pf) STAGE(t + 1, e, 2);
        __builtin_amdgcn_sched_barrier(0);
        __builtin_amdgcn_s_barrier();
        asm volatile("s_waitcnt lgkmcnt(0)" ::: "memory");
        __builtin_amdgcn_sched_barrier(0);
        __builtin_amdgcn_s_setprio(1);
#pragma unroll
        for (int i = 0; i < 4; i++)
#pragma unroll
            for (int j2 = 0; j2 < 4; j2++)
                acc[i + 4][j2] = __builtin_amdgcn_mfma_f32_16x16x32_bf16(
                    afQ[i], bfr[j2][0], acc[i + 4][j2], 0, 0, 0);
        __builtin_amdgcn_s_setprio(0);
        __builtin_amdgcn_sched_barrier(0);
        __builtin_amdgcn_s_barrier();
        __builtin_amdgcn_sched_barrier(0);

        // ---- phase 3: read Q3 (af mt0-3 kx1, bf kx1); stage B-h1(t+1)
#pragma unroll
        for (int i = 0; i < 4; i++)
            afQ[i] = *(const short8*)(bufd + cA + i * 1024 + ck1);
#pragma unroll
        for (int i = 0; i < 4; i++)
            bfr[i][1] = *(const short8*)(bufd + cB + i * 1024 + ck1);
        if (pf) STAGE(t + 1, e, 3);
        __builtin_amdgcn_sched_barrier(0);
        __builtin_amdgcn_s_barrier();
        asm volatile("s_waitcnt lgkmcnt(0)" ::: "memory");
        __builtin_amdgcn_sched_barrier(0);
        __builtin_amdgcn_s_setprio(1);
#pragma unroll
        for (int i = 0; i < 4; i++)
#pragma unroll
            for (int j2 = 0; j2 < 4; j2++)
                acc[i][j2] = __builtin_amdgcn_mfma_f32_16x16x32_bf16(
                    afQ[i], bfr[j2][1], acc[i][j2], 0, 0, 0);
        __builtin_amdgcn_s_setprio(0);
        __builtin_amdgcn_sched_barrier(0);
        __builtin_amdgcn_s_barrier();
        __builtin_amdgcn_sched_barrier(0);

        // ---- phase 4: read af mt4-7 kx1
#pragma unroll
        for (int i = 0; i < 4; i++)
            afQ[i] = *(const short8*)(bufd + cA + (i + 4) * 1024 + ck1);
        __builtin_amdgcn_sched_barrier(0);
        __builtin_amdgcn_s_barrier();
        asm volatile("s_waitcnt lgkmcnt(0)" ::: "memory");
        __builtin_amdgcn_sched_barrier(0);
        __builtin_amdgcn_s_setprio(1);
#pragma unroll
        for (int i = 0; i < 4; i++)
#pragma unroll
            for (int j2 = 0; j2 < 4; j2++)
                acc[i + 4][j2] = __builtin_amdgcn_mfma_f32_16x16x32_bf16(
                    afQ[i], bfr[j2][1], acc[i + 4][j2], 0, 0, 0);
        __builtin_amdgcn_s_setprio(0);
        __builtin_amdgcn_sched_barrier(0);
        __builtin_amdgcn_s_barrier();
        __builtin_amdgcn_sched_barrier(0);
    }
#undef STAGE

    float bn[4];
#pragma unroll
    for (int nt = 0; nt < 4; nt++) bn[nt] = bias[n0 + wn * 64 + nt * 16 + l15];

    if (MODE == 0) {
        float* C = (float*)Cout;
#pragma unroll
        for (int mt = 0; mt < 8; mt++) {
            int m = m0 + wm * 128 + mt * 16 + quad * 4;
#pragma unroll
            for (int nt = 0; nt < 4; nt++) {
                int n = n0 + wn * 64 + nt * 16 + l15;
#pragma unroll
                for (int r = 0; r < 4; r++)
                    C[(size_t)(m + r) * 2048 + n] = acc[mt][nt][r] + bn[nt];
            }
        }
    } else if (MODE == 3 || MODE == 4) {
        // bf16 (B,H,T,D) + fused RoPE (pair partner = lane^1 via shfl_xor)
        u16* C = (u16*)Cout;
#pragma unroll
        for (int mt = 0; mt < 8; mt++) {
            int m = m0 + wm * 128 + mt * 16 + quad * 4;
            int b = m >> 11, tr = m & 2047;
#pragma unroll
            for (int nt = 0; nt < 4; nt++) {
                int n = n0 + wn * 64 + nt * 16 + l15;
                int h = n >> 7, dd = n & 127;
                size_t base = ((size_t)(b * Hh + h) * Tt + tr) * Dd + dd;
#pragma unroll
                for (int r = 0; r < 4; r++) {
                    float v = acc[mt][nt][r] + bn[nt];
                    float other = __shfl_xor(v, 1, 64);
                    float c = ct[(tr + r) * 64 + (dd >> 1)];
                    float s = st[(tr + r) * 64 + (dd >> 1)];
                    // even d holds q0: q0*c - q1*s ; odd d holds q1: q0*s + q1*c
                    float rot = (dd & 1) ? (other * s + v * c)
                                         : (v * c - other * s);
                    if (MODE == 3) rot *= QSCALE;
                    C[base + (size_t)r * Dd] = f2bf(rot);
                }
            }
        }
    } else {  // MODE 2: V transposed (B,H,D,T), pack 4 consecutive t per lane
        u16* C = (u16*)Cout;
        const int b = m0 >> 11;
#pragma unroll
        for (int mt = 0; mt < 8; mt++) {
            int tloc = (m0 & 2047) + wm * 128 + mt * 16 + quad * 4;
#pragma unroll
            for (int nt = 0; nt < 4; nt++) {
                int n = n0 + wn * 64 + nt * 16 + l15;
                int h = n >> 7, dd = n & 127;
                union { ushort4 u; u16 s[4]; } pk;
#pragma unroll
                for (int r = 0; r < 4; r++) pk.s[r] = f2bf(acc[mt][nt][r] + bn[nt]);
                *(ushort4*)&C[((size_t)(b * Hh + h) * Dd + dd) * Tt + tloc] = pk.u;
            }
        }
    }
}

// ---- MFMA flash attention (causal), R5 structure (measured 211us): R0
// double-barrier staging + head-affine XCD remap + T5 setprio + tree
// reductions + defer-max. UNCHANGED this round.
__global__ __launch_bounds__(256) void flash_mfma(const u16* __restrict__ Q,
                                                  const u16* __restrict__ K,
                                                  const u16* __restrict__ Vt,
                                                  u16* __restrict__ O) {
    __shared__ u16 Ks[64 * 128];      // [kp][d], granule-XOR-swizzled by kp&15
    __shared__ u16 Vs[128 * 64];      // [d][kp], granule-XOR-swizzled by d&7
    __shared__ u16 Ps[4][32 * 72];    // per-wave P [q][kp], stride 72
    __shared__ float als[4][32];
    __shared__ float lls[4][32];
    const int tid  = threadIdx.x;
    const int lane = tid & 63, w = tid >> 6;
    const int l15  = lane & 15, quad = lane >> 4;

    // head-affine XCD remap: XCD x (= id&7) handles heads 8x..8x+7
    const int id  = blockIdx.x;                // 512 blocks
    const int bh  = (id & 7) * 8 + ((id >> 3) & 7);
    const int bxp = id >> 6;                   // 0..7 pairing slot

    // staging pointers (wave w owns chunks 4w..4w+3 of each buffer); bh-only
    const u16* Kg[4]; const u16* Vg[4];
    u16* KsD[4]; u16* VsD[4];
#pragma unroll
    for (int cc = 0; cc < 4; cc++) {
        int kp = w * 16 + cc * 4 + quad;
        int gs = l15 ^ (cc * 4 + quad);
        Kg[cc]  = K + ((size_t)bh * Tt + kp) * Dd + gs * 8;
        KsD[cc] = Ks + (w * 4 + cc) * 512;
        int d  = w * 32 + cc * 8 + (lane >> 3);
        int gv = (lane & 7) ^ (lane >> 3);
        Vg[cc]  = Vt + ((size_t)bh * Dd + d) * Tt + gv * 8;
        VsD[cc] = Vs + (w * 4 + cc) * 512;
    }

    const f32x4 zero4 = {0.f, 0.f, 0.f, 0.f};

    for (int ph = 0; ph < 2; ph++) {
        const int qt = ph ? bxp : 15 - bxp;
        const int q0 = qt * 128;

        // Q fragments (B-operand of S^T): q=nt*16+l15, d=ks*32+quad*8
        short8 qf[2][4];
        const u16* Qb = Q + ((size_t)bh * Tt + q0 + w * 32 + l15) * Dd + quad * 8;
#pragma unroll
        for (int nt = 0; nt < 2; nt++)
#pragma unroll
            for (int ks = 0; ks < 4; ks++)
                qf[nt][ks] = *(const short8*)(Qb + nt * 16 * Dd + ks * 32);

        f32x4 Oa[2][8];
#pragma unroll
        for (int mo = 0; mo < 2; mo++)
#pragma unroll
            for (int nt2 = 0; nt2 < 8; nt2++) Oa[mo][nt2] = zero4;
        float mrow[2] = {-INFINITY, -INFINITY};
        float lrow[2] = {0.f, 0.f};

        const int nkt = 2 * qt + 2;
        for (int kt = 0; kt < nkt; kt++) {
            __syncthreads();
#pragma unroll
            for (int cc = 0; cc < 4; cc++) gl_lds16(Kg[cc] + (size_t)kt * 64 * Dd, KsD[cc]);
#pragma unroll
            for (int cc = 0; cc < 4; cc++) gl_lds16(Vg[cc] + kt * 64, VsD[cc]);
            __syncthreads();

            // wave-level skip: tile fully masked for this wave's 32 q-rows
            if (kt * 64 > q0 + w * 32 + 31) continue;  // barriers already done

            // S^T = K * Q^T : rows kp = mt*16+quad*4+r, cols q = nt*16+l15
            f32x4 sc[4][2];
#pragma unroll
            for (int mt = 0; mt < 4; mt++) { sc[mt][0] = zero4; sc[mt][1] = zero4; }
            __builtin_amdgcn_s_setprio(1);
#pragma unroll
            for (int ks = 0; ks < 4; ks++) {
                short8 kf[4];
#pragma unroll
                for (int mt = 0; mt < 4; mt++)
                    kf[mt] = *(const short8*)(Ks + (mt * 16 + l15) * 128 +
                                              (((ks * 4 + quad) ^ l15) * 8));
#pragma unroll
                for (int mt = 0; mt < 4; mt++) {
                    sc[mt][0] = __builtin_amdgcn_mfma_f32_16x16x32_bf16(kf[mt], qf[0][ks], sc[mt][0], 0, 0, 0);
                    sc[mt][1] = __builtin_amdgcn_mfma_f32_16x16x32_bf16(kf[mt], qf[1][ks], sc[mt][1], 0, 0, 0);
                }
            }
            __builtin_amdgcn_s_setprio(0);

            const bool diag = (kt * 64 + 63 > q0 + w * 32);
            // online softmax in exp2 domain (scale*log2e pre-folded into Q)
#pragma unroll
            for (int nt = 0; nt < 2; nt++) {
                const int q_g = q0 + w * 32 + nt * 16 + l15;
                float sv[16];
#pragma unroll
                for (int mt = 0; mt < 4; mt++)
#pragma unroll
                    for (int r = 0; r < 4; r++)
                        sv[mt * 4 + r] = sc[mt][nt][r];
                if (diag) {
#pragma unroll
                    for (int mt = 0; mt < 4; mt++)
#pragma unroll
                        for (int r = 0; r < 4; r++) {
                            int kp_g = kt * 64 + mt * 16 + quad * 4 + r;
                            if (kp_g > q_g) sv[mt * 4 + r] = -INFINITY;
                        }
                }
                // tree max (depth 4)
                float m8[8], m4[4];
#pragma unroll
                for (int e = 0; e < 8; e++) m8[e] = fmaxf(sv[e], sv[e + 8]);
#pragma unroll
                for (int e = 0; e < 4; e++) m4[e] = fmaxf(m8[e], m8[e + 4]);
                float mx = fmaxf(fmaxf(m4[0], m4[1]), fmaxf(m4[2], m4[3]));
                mx = fmaxf(mx, __shfl_xor(mx, 16, 64));
                mx = fmaxf(mx, __shfl_xor(mx, 32, 64));
                float mnew = fmaxf(mrow[nt], mx);
                // defer-max (T13): keep old running max when growth <= 8
                mnew = (mnew - mrow[nt] <= 8.f) ? mrow[nt] : mnew;
                float alpha = exp2f(mrow[nt] - mnew);
                float pv[16];
#pragma unroll
                for (int e = 0; e < 16; e++) pv[e] = exp2f(sv[e] - mnew);
                // tree sum (depth 4)
                float s8[8], s4[4];
#pragma unroll
                for (int e = 0; e < 8; e++) s8[e] = pv[e] + pv[e + 8];
#pragma unroll
                for (int e = 0; e < 4; e++) s4[e] = s8[e] + s8[e + 4];
                float rs = (s4[0] + s4[1]) + (s4[2] + s4[3]);
                rs += __shfl_xor(rs, 16, 64);
                rs += __shfl_xor(rs, 32, 64);
                lrow[nt] = lrow[nt] * alpha + rs;
                mrow[nt] = mnew;
                if (quad == 0) als[w][nt * 16 + l15] = alpha;
#pragma unroll
                for (int mt = 0; mt < 4; mt++) {
                    union { ushort4 u; u16 s[4]; } pk;
#pragma unroll
                    for (int r = 0; r < 4; r++) pk.s[r] = f2bf(pv[mt * 4 + r]);
                    *(ushort4*)&Ps[w][(nt * 16 + l15) * 72 + mt * 16 + quad * 4] = pk.u;
                }
            }

            // rescale O by alpha; wave-uniform skip when all alphas == 1
            float ao[2][4];
            bool need = false;
#pragma unroll
            for (int mo = 0; mo < 2; mo++)
#pragma unroll
                for (int r = 0; r < 4; r++) {
                    ao[mo][r] = als[w][mo * 16 + quad * 4 + r];
                    need |= (ao[mo][r] != 1.f);
                }
            if (__any(need)) {
#pragma unroll
                for (int mo = 0; mo < 2; mo++)
#pragma unroll
                    for (int nt2 = 0; nt2 < 8; nt2++)
#pragma unroll
                        for (int r = 0; r < 4; r++) Oa[mo][nt2][r] *= ao[mo][r];
            }

            // O += P * V
            __builtin_amdgcn_s_setprio(1);
#pragma unroll
            for (int ks2 = 0; ks2 < 2; ks2++) {
                short8 pf[2];
#pragma unroll
                for (int mo = 0; mo < 2; mo++)
                    pf[mo] = *(const short8*)&Ps[w][(mo * 16 + l15) * 72 + ks2 * 32 + quad * 8];
#pragma unroll
                for (int nt2 = 0; nt2 < 8; nt2++) {
                    short8 vf = *(const short8*)(Vs + (nt2 * 16 + l15) * 64 +
                                                 (((ks2 * 4 + quad) ^ (l15 & 7)) * 8));
                    Oa[0][nt2] = __builtin_amdgcn_mfma_f32_16x16x32_bf16(pf[0], vf, Oa[0][nt2], 0, 0, 0);
                    Oa[1][nt2] = __builtin_amdgcn_mfma_f32_16x16x32_bf16(pf[1], vf, Oa[1][nt2], 0, 0, 0);
                }
            }
            __builtin_amdgcn_s_setprio(0);
        }

        // epilogue: normalize by l, store bf16 (B,T,ATTN)
        if (quad == 0) { lls[w][l15] = lrow[0]; lls[w][16 + l15] = lrow[1]; }
        float li[2][4];
#pragma unroll
        for (int mo = 0; mo < 2; mo++)
#pragma unroll
            for (int r = 0; r < 4; r++) li[mo][r] = 1.f / lls[w][mo * 16 + quad * 4 + r];
        const int b = bh >> 4, h = bh & 15;
#pragma unroll
        for (int mo = 0; mo < 2; mo++)
#pragma unroll
            for (int r = 0; r < 4; r++) {
                size_t ro = ((size_t)b * Tt + q0 + w * 32 + mo * 16 + quad * 4 + r) * ATTN
                            + h * Dd;
#pragma unroll
                for (int nt2 = 0; nt2 < 8; nt2++)
                    O[ro + nt2 * 16 + l15] = f2bf(Oa[mo][nt2][r] * li[mo][r]);
            }
    }
}

extern "C" void kernel_launch(void* const* d_in, const int* in_sizes, int n_in,
                              void* d_out, int out_size, void* d_ws, size_t ws_size,
                              hipStream_t stream) {
    const float* x    = (const float*)d_in[0];
    const float* wq_w = (const float*)d_in[3];
    const float* wq_b = (const float*)d_in[4];
    const float* wk_w = (const float*)d_in[5];
    const float* wk_b = (const float*)d_in[6];
    const float* wv_w = (const float*)d_in[7];
    const float* wv_b = (const float*)d_in[8];
    const float* wo_w = (const float*)d_in[9];
    const float* wo_b = (const float*)d_in[10];

    char* ws = (char*)d_ws;
    u16*   qb  = (u16*)(ws);                    // 32 MiB bf16 (B,H,T,D)
    u16*   kb  = (u16*)(ws + 33554432);         // 32 MiB bf16 (B,H,T,D)
    u16*   vtb = (u16*)(ws + 67108864);         // 32 MiB bf16 (B,H,D,T)
    u16*   xb  = (u16*)(ws + 100663296);        // 32 MiB bf16 x (8192x2048)
    u16*   obb = xb;                            // flash out aliases xb (x dead)
    u16*   wqb = (u16*)(ws + 134217728);        // 8 MiB each
    u16*   wkb = (u16*)(ws + 142606336);
    u16*   wvb = (u16*)(ws + 150994944);
    u16*   wob = (u16*)(ws + 159383552);
    float* ct  = (float*)(ws + 167772160);      // 512 KiB
    float* st  = (float*)(ws + 168296448);      // 512 KiB

    freq_kernel<<<512, 256, 0, stream>>>(ct, st);
    cvt_kernel<<<16384, 256, 0, stream>>>(x, xb, 4194304);
    cvtw_kernel<<<dim3(4096, 4), 256, 0, stream>>>(wq_w, wk_w, wv_w, wo_w,
                                                   wqb, wkb, wvb, wob);

    gemm_mfma<3><<<256, 512, 131072, stream>>>(xb, wqb, wq_b, qb, ct, st);
    gemm_mfma<4><<<256, 512, 131072, stream>>>(xb, wkb, wk_b, kb, ct, st);
    gemm_mfma<2><<<256, 512, 131072, stream>>>(xb, wvb, wv_b, vtb, ct, st);
    flash_mfma<<<512, 256, 0, stream>>>(qb, kb, vtb, obb);
    gemm_mfma<0><<<256, 512, 131072, stream>>>(obb, wob, wo_b, (float*)d_out, ct, st);
}